// Round 5
// baseline (1637.751 us; speedup 1.0000x reference)
//
#include <hip/hip_runtime.h>
#include <stdint.h>

#define H_   16
#define DK_  128
#define DV_  128
#define HID_ 2048
#define KS_  4
#define B_   4
#define T_   2048
#define BT_  (B_*T_)     // 8192
#define QKVC (3*HID_)    // 6144
#define C_   32          // scan chunk length
#define RS_  16          // state rows per block
#define NC_  (T_/C_)     // 64 chunks

typedef unsigned short u16;
typedef short  bf16x8 __attribute__((ext_vector_type(8)));
typedef u16    u16x8  __attribute__((ext_vector_type(8)));
typedef u16    u16x4  __attribute__((ext_vector_type(4)));
typedef float  f32x4  __attribute__((ext_vector_type(4)));

__device__ __forceinline__ float b2f(u16 u){
  union { unsigned int i; float f; } v; v.i = ((unsigned int)u) << 16; return v.f;
}
__device__ __forceinline__ u16 f2b(float f){
  unsigned int x = __float_as_uint(f);
  unsigned int r = (x + 0x7FFFu + ((x >> 16) & 1u)) >> 16;
  return (u16)r;
}
__device__ __forceinline__ float sigm(float x){ return 1.0f / (1.0f + __expf(-x)); }

#define MFMA16(a,b,c) __builtin_amdgcn_mfma_f32_16x16x32_bf16((a),(b),(c),0,0,0)

// ---------------- x conversion: f32 (bf16-valued) -> bf16, vectorized ----------------
__global__ __launch_bounds__(256) void cvt_x_k(const f32x4* __restrict__ src,
                                               u16x4* __restrict__ dst, int n4)
{
  int i0 = blockIdx.x * 256 + threadIdx.x;
  int stride = gridDim.x * 256;
  for (int i = i0; i < n4; i += stride) {
    f32x4 v = src[i];
    u16x4 r; r[0] = f2b(v[0]); r[1] = f2b(v[1]); r[2] = f2b(v[2]); r[3] = f2b(v[3]);
    dst[i] = r;
  }
}

// ---------------- small-tensor conversions ----------------
__global__ __launch_bounds__(256) void cvt_small_k(
    const float* __restrict__ qcw, const float* __restrict__ kcw, const float* __restrict__ vcw,
    const float* __restrict__ qcb, const float* __restrict__ kcb, const float* __restrict__ vcb,
    const float* __restrict__ ba,  const float* __restrict__ bb,
    const float* __restrict__ lnw, const float* __restrict__ lnb,
    u16* __restrict__ canon)
{
  int i = blockIdx.x * 256 + threadIdx.x;
  if (i >= 31008) return;
  float v;
  if (i < 24576) {
    const float* s = (i < 8192) ? qcw : (i < 16384) ? kcw : vcw;
    v = s[i & 8191];
  } else if (i < 30720) {
    int j = i - 24576;
    const float* s = (j < 2048) ? qcb : (j < 4096) ? kcb : vcb;
    v = s[j & 2047];
  } else if (i < 30752) {
    int j = i - 30720;
    v = (j < 16) ? ba[j] : bb[j - 16];
  } else {
    int j = i - 30752;
    v = (j < 128) ? lnw[j] : lnb[j - 128];
  }
  canon[i] = f2b(v);
}

// ---------------- batched transpose ----------------
__global__ __launch_bounds__(256) void transpose_b(const float* __restrict__ s0,
                                                   const float* __restrict__ s1,
                                                   const float* __restrict__ s2,
                                                   u16* __restrict__ dst,
                                                   int R, int C)
{
  int z = blockIdx.z;
  const float* src = (z == 0) ? s0 : (z == 1) ? s1 : s2;
  u16* d = dst + (size_t)z * R * C;
  __shared__ u16 t[32][33];
  int bx = blockIdx.x * 32;
  int by = blockIdx.y * 32;
  int lx = threadIdx.x & 31, ly = threadIdx.x >> 5;
  #pragma unroll
  for (int i = 0; i < 4; ++i) {
    int r = by + ly + i * 8, c = bx + lx;
    if (r < R && c < C) t[ly + i * 8][lx] = f2b(src[(size_t)r * C + c]);
  }
  __syncthreads();
  #pragma unroll
  for (int i = 0; i < 4; ++i) {
    int r = bx + ly + i * 8;
    int c = by + lx;
    if (r < C && c < R) d[(size_t)r * R + c] = t[lx][ly + i * 8];
  }
}

// ---------------- m97-style bf16 GEMM ----------------
#define BM 128
#define BN 128
#define BK 32

__device__ __forceinline__ void gload_lds16(const void* gp, void* lp){
  __builtin_amdgcn_global_load_lds(
      (const __attribute__((address_space(1))) void*)gp,
      (__attribute__((address_space(3))) void*)lp, 16, 0, 0);
}

__global__ __launch_bounds__(256) void gemm_bt(const u16* __restrict__ A, int lda,
                                               const u16* __restrict__ Bt, int ldb,
                                               void* __restrict__ C, int ldc,
                                               int K, int out_f32)
{
  __shared__ u16 lsA[BM * BK];
  __shared__ u16 lsB[BN * BK];
  int tid = threadIdx.x, wave = tid >> 6, lane = tid & 63;
  int m0 = blockIdx.y * BM, n0 = blockIdx.x * BN;
  int wm = (wave >> 1) * 64, wn = (wave & 1) * 64;
  int srow = lane >> 2;
  int skel = (lane & 3) * 8;
  int quad = lane >> 4, l16 = lane & 15;

  f32x4 acc[4][4];
  #pragma unroll
  for (int mi = 0; mi < 4; ++mi)
    #pragma unroll
    for (int ni = 0; ni < 4; ++ni)
      #pragma unroll
      for (int r = 0; r < 4; ++r) acc[mi][ni][r] = 0.0f;

  for (int k0 = 0; k0 < K; k0 += BK) {
    __syncthreads();
    #pragma unroll
    for (int i = 0; i < 2; ++i) {
      int row = wave * 32 + i * 16 + srow;
      gload_lds16(A  + (size_t)(m0 + row) * lda + k0 + skel,
                  lsA + (wave * 2048 + i * 1024) / 2);
      gload_lds16(Bt + (size_t)(n0 + row) * ldb + k0 + skel,
                  lsB + (wave * 2048 + i * 1024) / 2);
    }
    __syncthreads();

    const bf16x8* fA = (const bf16x8*)lsA;
    const bf16x8* fB = (const bf16x8*)lsB;
    bf16x8 af[4], bg[4];
    #pragma unroll
    for (int mi = 0; mi < 4; ++mi) af[mi] = fA[(wm + mi * 16 + l16) * 4 + quad];
    #pragma unroll
    for (int ni = 0; ni < 4; ++ni) bg[ni] = fB[(wn + ni * 16 + l16) * 4 + quad];
    #pragma unroll
    for (int mi = 0; mi < 4; ++mi)
      #pragma unroll
      for (int ni = 0; ni < 4; ++ni)
        acc[mi][ni] = MFMA16(af[mi], bg[ni], acc[mi][ni]);
  }

  #pragma unroll
  for (int mi = 0; mi < 4; ++mi)
    #pragma unroll
    for (int ni = 0; ni < 4; ++ni)
      #pragma unroll
      for (int r = 0; r < 4; ++r) {
        int m = m0 + wm + mi * 16 + quad * 4 + r;
        int n = n0 + wn + ni * 16 + l16;
        if (out_f32) ((float*)C)[(size_t)m * ldc + n] = acc[mi][ni][r];
        else         ((u16*)C)[(size_t)m * ldc + n] = f2b(acc[mi][ni][r]);
      }
}

// ---------------- alpha/beta ----------------
__global__ __launch_bounds__(256) void ab_k(const u16* __restrict__ x,
                                            const u16* __restrict__ WabT,
                                            const u16* __restrict__ ba,
                                            const u16* __restrict__ bb,
                                            float* __restrict__ ab)
{
  int j = threadIdx.x & 31, rl = threadIdx.x >> 5;
  int row = blockIdx.x * 8 + rl;
  const u16x8* xr = (const u16x8*)(x + (size_t)row * HID_);
  const u16x8* wr = (const u16x8*)(WabT + (size_t)j * HID_);
  float acc = 0.f;
  for (int k = 0; k < HID_ / 8; ++k) {
    u16x8 xv = xr[k], wv = wr[k];
    #pragma unroll
    for (int i = 0; i < 8; ++i) acc += b2f(xv[i]) * b2f(wv[i]);
  }
  float bias = (j < 16) ? b2f(ba[j]) : b2f(bb[j - 16]);
  float sg = sigm(acc + bias);
  if (j < 16) ab[(size_t)row * 16 + j] = sg;
  else        ab[(size_t)BT_ * 16 + (size_t)row * 16 + (j - 16)] = sg;
}

// ---------------- causal dwconv (KS=4) + silu ----------------
__global__ __launch_bounds__(256) void conv_silu_k(const u16* __restrict__ in,
                                                   const u16* __restrict__ cwv,
                                                   const u16* __restrict__ cbv,
                                                   u16* __restrict__ out)
{
  int idx  = blockIdx.x * 256 + threadIdx.x;
  int col8 = idx % (QKVC / 8);
  int t    = idx / (QKVC / 8);
  int col  = col8 * 8;
  int s = col >> 11;

  u16 wl[32];
  #pragma unroll
  for (int i = 0; i < 4; ++i)
    *(u16x8*)(wl + i * 8) = *(const u16x8*)(cwv + (size_t)col * KS_ + i * 8);
  u16x8 bv = *(const u16x8*)(cbv + col);

  float acc[8];
  #pragma unroll
  for (int j = 0; j < 8; ++j) acc[j] = b2f(bv[j]);

  #pragma unroll
  for (int tap = 0; tap < KS_; ++tap) {
    int tt = t - 3 + tap;
    if (tt >= 0) {
      u16x8 xv = *(const u16x8*)(in + (size_t)tt * QKVC + col);
      #pragma unroll
      for (int j = 0; j < 8; ++j) acc[j] = fmaf(b2f(xv[j]), b2f(wl[j * 4 + tap]), acc[j]);
    }
  }
  float scale = (s == 1) ? 0.08838834764831845f : 1.0f;
  u16x8 rv;
  #pragma unroll
  for (int j = 0; j < 8; ++j) {
    float a = acc[j];
    rv[j] = f2b(a * sigm(a) * scale);
  }
  *(u16x8*)(out + (size_t)t * QKVC + col) = rv;
}

// ---------------- chunked gated delta-rule scan (UT transform, MFMA) ----------------
// R5 changes vs R4 (same math, verified absmax-neutral in R4):
//  * RS=16, 512 blocks = 8 row-slices x 64 chains -> 2 blocks/CU so one block's
//    barrier phases overlap the other's (R4: 1 block/CU, occupancy 11.8%).
//    Slice stride 64 == 0 mod 8 keeps all slices of a chain on one XCD.
//  * T14 async-STAGE: chunk c+1's K/Q/V/gate loads issue into regs right after
//    chunk c's LDS writes; reg-dest loads survive __syncthreads, removing
//    L2/HBM latency from the per-chunk critical path.
//  * Bank conflicts: KT column-block XOR swizzle (16-way -> ~8-way on the
//    transposed write; reads ~2-way), f32 score arrays padded to odd strides.
//  * ph2 rebalanced over 4 waves; G-build runs concurrently with the solve.
__global__ __launch_bounds__(256) void chunk_scan_k(const u16* __restrict__ qkv,
                                                    const float* __restrict__ ab,
                                                    u16* __restrict__ o)
{
  __shared__ __align__(16) char smem[50688];
  u16 (*Kim)[136]  = (u16(*)[136])(smem);            // [32][136]
  u16 (*Qim)[136]  = (u16(*)[136])(smem + 8704);     // [32][136]
  u16 (*Sh)[136]   = (u16(*)[136])(smem + 17408);    // [16][136]
  u16 (*Sl)[136]   = (u16(*)[136])(smem + 21760);    // [16][136]
  u16 (*KT)[40]    = (u16(*)[40])(smem + 26112);     // [128][40], col-block swizzled
  u16 (*Vim)[16]   = (u16(*)[16])(smem + 36352);     // [32][16]
  float (*KK)[33]  = (float(*)[33])(smem + 37376);   // [32][33]
  float (*KQ)[33]  = (float(*)[33])(smem + 41600);   // [32][33]
  float (*SK0)[17] = (float(*)[17])(smem + 45824);   // [32][17]
  float (*SQ0)[17] = (float(*)[17])(smem + 48000);   // [32][17]
  float (*PL4)[4]  = (float(*)[4])(smem + 50176);    // [32]{s_t,b_t,1/P_t,P_t}
  // overlays: Qim region free after ph2
  float (*U)[17]   = (float(*)[17])(smem + 8704);    // [32][17]
  u16 (*Uth)[40]   = (u16(*)[40])(smem + 10880);     // [16][40]
  u16 (*Utl)[40]   = (u16(*)[40])(smem + 12160);
  u16 (*Uch)[40]   = (u16(*)[40])(smem + 13440);
  u16 (*Ucl)[40]   = (u16(*)[40])(smem + 14720);
  // overlays: Sh/Sl region free after ph2
  u16 (*Gh)[40]    = (u16(*)[40])(smem + 17408);     // [32][40]
  u16 (*Gl)[40]    = (u16(*)[40])(smem + 21760);

  int bid = blockIdx.x;
  int chain = bid & 63, rblk = bid >> 6;             // rblk in [0,8)
  int b = chain >> 4, h = chain & 15;
  int tid = threadIdx.x, wv = tid >> 6, lane = tid & 63;
  int l16 = lane & 15, quad = lane >> 4;

  const u16* kbase = qkv + (size_t)b * T_ * QKVC + HID_ + h * DK_;
  const u16* qbase = qkv + (size_t)b * T_ * QKVC + h * DK_;
  const u16* vbase = qkv + (size_t)b * T_ * QKVC + 2 * HID_ + h * DV_ + rblk * RS_;
  const float* abase = ab + (size_t)b * T_ * 16 + h;
  const float* bbase = abase + (size_t)BT_ * 16;
  u16* obase = o + (size_t)b * T_ * 2048 + h * DV_ + rblk * RS_;

  // persistent state: 16 rows x 32 cols per wave (cols [wv*32, wv*32+32))
  f32x4 st[2];
  #pragma unroll
  for (int ct = 0; ct < 2; ++ct)
    #pragma unroll
    for (int r = 0; r < 4; ++r) st[ct][r] = 0.f;

  int jb = tid - 64;
  u16x8 stg[6];
  float avp = 0.f;

  // issue chunk-c loads into registers (T14: survive barriers, consumed next ph1)
  auto LD = [&](int c) {
    int t0 = c * C_;
    if (wv == 0) {
      avp = (lane < 32) ? abase[(size_t)(t0 + lane) * 16]
                        : bbase[(size_t)(t0 + lane - 32) * 16];
    } else {
      #pragma unroll
      for (int it = 0; it < 6; ++it) {
        int j = jb + it * 192;
        if (j < 512) {
          int t = j >> 4, g = j & 15;
          stg[it] = *(const u16x8*)(kbase + (size_t)(t0 + t) * QKVC + g * 8);
        } else if (j < 1024) {
          int j2 = j - 512, t = j2 >> 4, g = j2 & 15;
          stg[it] = *(const u16x8*)(qbase + (size_t)(t0 + t) * QKVC + g * 8);
        } else if (j < 1088) {
          int j2 = j - 1024, t = j2 >> 1, rg = j2 & 1;
          stg[it] = *(const u16x8*)(vbase + (size_t)(t0 + t) * QKVC + rg * 8);
        }
      }
    }
  };

  LD(0);

  for (int c = 0; c < NC_; ++c) {
    int t0 = c * C_;

    // ---- ph1: state image + staging writes + gates; then prefetch c+1 ----
    #pragma unroll
    for (int ct = 0; ct < 2; ++ct)
      #pragma unroll
      for (int r = 0; r < 4; ++r) {
        float s = st[ct][r];
        u16 hi = f2b(s);
        float lo = s - b2f(hi);
        int row = quad * 4 + r;
        int col = wv * 32 + ct * 16 + l16;
        Sh[row][col] = hi;
        Sl[row][col] = f2b(lo);
      }

    if (wv == 0) {
      float av = avp;
      float p = av;
      #pragma unroll
      for (int d = 1; d < 32; d <<= 1) {
        float up = __shfl_up(p, d);
        if (lane >= d && lane < 32) p *= up;
      }
      float pm1 = __shfl_up(p, 1);
      float bt = __shfl(av, lane + 32);
      if (lane < 32) {
        if (lane == 0) pm1 = 1.f;
        f32x4 g;
        g[0] = bt * pm1; g[1] = bt; g[2] = 1.0f / p; g[3] = p;
        *(f32x4*)PL4[lane] = g;
      }
    } else {
      #pragma unroll
      for (int it = 0; it < 6; ++it) {
        int j = jb + it * 192;
        if (j < 512) {
          int t = j >> 4, g = j & 15;
          *(u16x8*)&Kim[t][g * 8] = stg[it];
          int tb = t >> 3, tl = t & 7;
          int blk = (tb ^ (g & 3)) << 3;        // 2-bit XOR swizzle
          #pragma unroll
          for (int e = 0; e < 8; ++e)
            KT[g * 8 + e][blk + tl] = stg[it][e];
        } else if (j < 1024) {
          int j2 = j - 512, t = j2 >> 4, g = j2 & 15;
          *(u16x8*)&Qim[t][g * 8] = stg[it];
        } else if (j < 1088) {
          int j2 = j - 1024, t = j2 >> 1, rg = j2 & 1;
          *(u16x8*)&Vim[t][rg * 8] = stg[it];
        }
      }
    }
    if (c + 1 < NC_) LD(c + 1);
    __syncthreads();

    // ---- ph2: KK / KQ / SK0 / SQ0, rebalanced over 4 waves ----
    if (wv == 0) {
      #pragma unroll
      for (int mt = 0; mt < 2; ++mt) {
        f32x4 acc = {0.f,0.f,0.f,0.f};
        #pragma unroll
        for (int ks = 0; ks < 4; ++ks) {
          bf16x8 A  = *(const bf16x8*)&Kim[mt * 16 + l16][ks * 32 + quad * 8];
          bf16x8 Bh = *(const bf16x8*)&Sh[l16][ks * 32 + quad * 8];
          bf16x8 Bl = *(const bf16x8*)&Sl[l16][ks * 32 + quad * 8];
          acc = MFMA16(A, Bh, acc);
          acc = MFMA16(A, Bl, acc);
        }
        #pragma unroll
        for (int r = 0; r < 4; ++r) SK0[mt * 16 + quad * 4 + r][l16] = acc[r];
      }
    } else if (wv == 1) {
      const int mts[3] = {0, 1, 1}, nts[3] = {0, 0, 1};
      #pragma unroll
      for (int jj = 0; jj < 3; ++jj) {
        int mt = mts[jj], nt = nts[jj];
        f32x4 acc = {0.f,0.f,0.f,0.f};
        #pragma unroll
        for (int ks = 0; ks < 4; ++ks) {
          bf16x8 A = *(const bf16x8*)&Kim[mt * 16 + l16][ks * 32 + quad * 8];
          bf16x8 B = *(const bf16x8*)&Kim[nt * 16 + l16][ks * 32 + quad * 8];
          acc = MFMA16(A, B, acc);
        }
        #pragma unroll
        for (int r = 0; r < 4; ++r) KK[mt * 16 + quad * 4 + r][nt * 16 + l16] = acc[r];
      }
    } else {
      int nt = wv - 2;
      #pragma unroll
      for (int mt = 0; mt < 2; ++mt) {
        f32x4 acc = {0.f,0.f,0.f,0.f};
        #pragma unroll
        for (int ks = 0; ks < 4; ++ks) {
          bf16x8 A = *(const bf16x8*)&Qim[mt * 16 + l16][ks * 32 + quad * 8];
          bf16x8 B = *(const bf16x8*)&Kim[nt * 16 + l16][ks * 32 + quad * 8];
          acc = MFMA16(A, B, acc);
        }
        #pragma unroll
        for (int r = 0; r < 4; ++r) KQ[mt * 16 + quad * 4 + r][nt * 16 + l16] = acc[r];
      }
      int mt = nt;
      f32x4 acc = {0.f,0.f,0.f,0.f};
      #pragma unroll
      for (int ks = 0; ks < 4; ++ks) {
        bf16x8 A  = *(const bf16x8*)&Qim[mt * 16 + l16][ks * 32 + quad * 8];
        bf16x8 Bh = *(const bf16x8*)&Sh[l16][ks * 32 + quad * 8];
        bf16x8 Bl = *(const bf16x8*)&Sl[l16][ks * 32 + quad * 8];
        acc = MFMA16(A, Bh, acc);
        acc = MFMA16(A, Bl, acc);
      }
      #pragma unroll
      for (int r = 0; r < 4; ++r) SQ0[mt * 16 + quad * 4 + r][l16] = acc[r];
    }
    __syncthreads();

    // ---- ph3: wave0 triangular solve || waves1-3 build G ----
    if (wv == 0) {
      if (lane < 16) {
        float ub[C_];
        #pragma unroll
        for (int t = 0; t < C_; ++t) {
          f32x4 g = *(const f32x4*)PL4[t];
          float u = g[0] * SK0[t][lane] - g[1] * b2f(Vim[t][lane]);
          float acc = 0.f;
          #pragma unroll
          for (int i = 0; i < t; ++i) acc = fmaf(KK[t][i], ub[i], acc);
          u = fmaf(-g[0], acc, u);
          U[t][lane] = u;
          ub[t] = g[2] * u;
        }
      }
    } else {
      #pragma unroll
      for (int it = 0; it < 6; ++it) {
        int idx = jb + it * 192;
        if (idx < 1024) {
          int t = idx >> 5, i = idx & 31;
          float gv = (i <= t) ? (-PL4[t][3] * PL4[i][2] * KQ[t][i]) : 0.f;
          u16 hh = f2b(gv);
          Gh[t][i] = hh;
          Gl[t][i] = f2b(gv - b2f(hh));
        }
      }
    }
    __syncthreads();

    // ---- ph4: u hi/lo images (all threads) ----
    {
      float PL31 = PL4[31][3];
      #pragma unroll
      for (int e = 0; e < 2; ++e) {
        int idx = tid * 2 + e;
        int row = idx & 15, i = idx >> 4;
        float uv = U[i][row];
        u16 h1 = f2b(uv);
        Uth[row][i] = h1; Utl[row][i] = f2b(uv - b2f(h1));
        float ucv = -PL31 * PL4[i][2] * uv;
        u16 h2 = f2b(ucv);
        Uch[row][i] = h2; Ucl[row][i] = f2b(ucv - b2f(h2));
      }
    }
    __syncthreads();

    // ---- ph5: state update (all waves) + outputs (waves 0,1) ----
    {
      float PL31 = PL4[31][3];
      bf16x8 Ah = *(const bf16x8*)&Uch[l16][quad * 8];
      bf16x8 Al = *(const bf16x8*)&Ucl[l16][quad * 8];
      #pragma unroll
      for (int ct = 0; ct < 2; ++ct) {
        int col = wv * 32 + ct * 16 + l16;
        bf16x8 Bk = *(const bf16x8*)&KT[col][(quad ^ ((col >> 3) & 3)) << 3];
        f32x4 cacc;
        #pragma unroll
        for (int r = 0; r < 4; ++r) cacc[r] = PL31 * st[ct][r];
        cacc = MFMA16(Ah, Bk, cacc);
        cacc = MFMA16(Al, Bk, cacc);
        st[ct] = cacc;
      }
      if (wv < 2) {
        int mt = wv;
        bf16x8 Agh = *(const bf16x8*)&Gh[mt * 16 + l16][quad * 8];
        bf16x8 Agl = *(const bf16x8*)&Gl[mt * 16 + l16][quad * 8];
        bf16x8 Buh = *(const bf16x8*)&Uth[l16][quad * 8];
        bf16x8 Bul = *(const bf16x8*)&Utl[l16][quad * 8];
        f32x4 oacc;
        #pragma unroll
        for (int r = 0; r < 4; ++r) {
          int t = mt * 16 + quad * 4 + r;
          oacc[r] = PL4[t][3] * SQ0[t][l16];
        }
        oacc = MFMA16(Agh, Buh, oacc);
        oacc = MFMA16(Agh, Bul, oacc);
        oacc = MFMA16(Agl, Buh, oacc);
        #pragma unroll
        for (int r = 0; r < 4; ++r) {
          int t = mt * 16 + quad * 4 + r;
          obase[(size_t)(t0 + t) * 2048 + l16] = f2b(oacc[r]);
        }
      }
    }
    __syncthreads();
  }
}

// ---------------- LayerNorm(DV) * sigmoid(g) ----------------
__global__ __launch_bounds__(256) void ln_gate_k(const u16* __restrict__ o_raw,
                                                 const u16* __restrict__ g,
                                                 const u16* __restrict__ lnw,
                                                 const u16* __restrict__ lnb,
                                                 u16* __restrict__ o_ln)
{
  int gid = blockIdx.x * 4 + (threadIdx.x >> 6);
  int lane = threadIdx.x & 63;
  int row = gid >> 4, h = gid & 15;
  size_t ofs = (size_t)row * 2048 + h * 128 + lane * 2;
  unsigned int e2 = *(const unsigned int*)(o_raw + ofs);
  float ex = b2f((u16)(e2 & 0xffff)), ey = b2f((u16)(e2 >> 16));
  float s = ex + ey, ss = ex * ex + ey * ey;
  #pragma unroll
  for (int m = 1; m < 64; m <<= 1) { s += __shfl_xor(s, m); ss += __shfl_xor(ss, m); }
  float mean = s * (1.f / 128.f);
  float var  = ss * (1.f / 128.f) - mean * mean;
  float rstd = rsqrtf(fmaxf(var, 0.f) + 1e-5f);
  float w0 = b2f(lnw[lane * 2]), w1 = b2f(lnw[lane * 2 + 1]);
  float b0 = b2f(lnb[lane * 2]), b1 = b2f(lnb[lane * 2 + 1]);
  unsigned int g2 = *(const unsigned int*)(g + ofs);
  float g0 = sigm(b2f((u16)(g2 & 0xffff))), g1 = sigm(b2f((u16)(g2 >> 16)));
  float r0 = ((ex - mean) * rstd * w0 + b0) * g0;
  float r1 = ((ey - mean) * rstd * w1 + b1) * g1;
  *(unsigned int*)(o_ln + ofs) = (unsigned int)f2b(r0) | ((unsigned int)f2b(r1) << 16);
}

// ---------------- host launch ----------------
extern "C" void kernel_launch(void* const* d_in, const int* in_sizes, int n_in,
                              void* d_out, int out_size, void* d_ws, size_t ws_size,
                              hipStream_t stream)
{
  const float* x   = (const float*)d_in[0];
  const float* Wq  = (const float*)d_in[1];
  const float* Wk  = (const float*)d_in[2];
  const float* Wv  = (const float*)d_in[3];
  const float* Wa  = (const float*)d_in[4];
  const float* ba  = (const float*)d_in[5];
  const float* Wb  = (const float*)d_in[6];
  const float* bb  = (const float*)d_in[7];
  const float* Wg  = (const float*)d_in[8];
  const float* Wo  = (const float*)d_in[9];
  const float* qcw = (const float*)d_in[10];
  const float* qcb = (const float*)d_in[11];
  const float* kcw = (const float*)d_in[12];
  const float* kcb = (const float*)d_in[13];
  const float* vcw = (const float*)d_in[14];
  const float* vcb = (const float*)d_in[15];
  const float* lnw = (const float*)d_in[16];
  const float* lnb = (const float*)d_in[17];
  (void)in_sizes; (void)n_in; (void)out_size;

  char* ws = (char*)d_ws;
  size_t off = 0;
  auto alloc = [&](size_t bytes) -> void* {
    void* p = ws + off; off += (bytes + 255) & ~(size_t)255; return p;
  };
  u16* WT    = (u16*)alloc((size_t)3 * HID_ * HID_ * 2);
  u16* WabT  = (u16*)alloc((size_t)32 * HID_ * 2);
  u16* xc    = (u16*)alloc((size_t)BT_ * HID_ * 2);
  u16* canon = (u16*)alloc((size_t)31008 * 2);
  u16* preC  = (u16*)alloc((size_t)BT_ * HID_ * 2 * 2);
  u16* post  = (u16*)alloc((size_t)BT_ * QKVC * 2);
  float* abuf = (float*)alloc((size_t)2 * BT_ * 16 * 4);
  if (off > ws_size) return;

  u16* cw_c  = canon;
  u16* cb_c  = canon + 24576;
  u16* ba_c  = canon + 30720;
  u16* bb_c  = canon + 30736;
  u16* lnw_c = canon + 30752;
  u16* lnb_c = canon + 30880;

  u16* o_raw = preC;
  u16* g_raw = post;
  u16* o_ln  = post + (size_t)BT_ * HID_;
  u16* WTg   = WT;

  dim3 tb(256);

  cvt_x_k<<<dim3(4096), tb, 0, stream>>>((const f32x4*)x, (u16x4*)xc, BT_ * HID_ / 4);
  cvt_small_k<<<dim3(122), tb, 0, stream>>>(qcw, kcw, vcw, qcb, kcb, vcb, ba, bb, lnw, lnb, canon);

  transpose_b<<<dim3(64, 64, 3), tb, 0, stream>>>(Wq, Wk, Wv, WT, HID_, HID_);
  transpose_b<<<dim3(1, 64, 2), tb, 0, stream>>>(Wa, Wb, Wb, WabT, HID_, 16);

  for (int b = 0; b < B_; ++b) {
    const u16* xb = xc + (size_t)b * T_ * HID_;
    gemm_bt<<<dim3(QKVC / BN, T_ / BM), tb, 0, stream>>>(xb, HID_, WT, HID_, preC, QKVC, HID_, 0);
    conv_silu_k<<<dim3(T_ * (QKVC / 8) / 256), tb, 0, stream>>>(
        preC, cw_c, cb_c, post + (size_t)b * T_ * QKVC);
  }

  transpose_b<<<dim3(64, 64, 2), tb, 0, stream>>>(Wg, Wo, Wo, WTg, HID_, HID_);

  ab_k<<<dim3(BT_ / 8), tb, 0, stream>>>(xc, WabT, ba_c, bb_c, abuf);

  // chunked scan: 512 blocks = 8 row-slices x 64 chains, 2 blocks/CU
  chunk_scan_k<<<dim3(512), tb, 0, stream>>>(post, abuf, o_raw);

  gemm_bt<<<dim3(HID_ / BN, BT_ / BM), tb, 0, stream>>>(xc, HID_, WTg, HID_, g_raw, HID_, HID_, 0);

  ln_gate_k<<<dim3(BT_ * H_ / 4), tb, 0, stream>>>(o_raw, g_raw, lnw_c, lnb_c, o_ln);

  gemm_bt<<<dim3(HID_ / BN, BT_ / BM), tb, 0, stream>>>(o_ln, HID_,
      WT + (size_t)HID_ * HID_, HID_, d_out, HID_, HID_, 1);
}

// Round 6
// 1407.703 us; speedup vs baseline: 1.1634x; 1.1634x over previous
//
#include <hip/hip_runtime.h>
#include <stdint.h>

#define H_   16
#define DK_  128
#define DV_  128
#define HID_ 2048
#define KS_  4
#define B_   4
#define T_   2048
#define BT_  (B_*T_)     // 8192
#define QKVC (3*HID_)    // 6144
#define C_   32          // scan chunk length
#define RS_  32          // state rows per block
#define NC_  (T_/C_)     // 64 chunks

typedef unsigned short u16;
typedef short  bf16x8 __attribute__((ext_vector_type(8)));
typedef u16    u16x8  __attribute__((ext_vector_type(8)));
typedef u16    u16x4  __attribute__((ext_vector_type(4)));
typedef float  f32x4  __attribute__((ext_vector_type(4)));

__device__ __forceinline__ float b2f(u16 u){
  union { unsigned int i; float f; } v; v.i = ((unsigned int)u) << 16; return v.f;
}
__device__ __forceinline__ u16 f2b(float f){
  unsigned int x = __float_as_uint(f);
  unsigned int r = (x + 0x7FFFu + ((x >> 16) & 1u)) >> 16;
  return (u16)r;
}
__device__ __forceinline__ float sigm(float x){ return 1.0f / (1.0f + __expf(-x)); }

#define MFMA16(a,b,c) __builtin_amdgcn_mfma_f32_16x16x32_bf16((a),(b),(c),0,0,0)

// ---------------- x conversion: f32 (bf16-valued) -> bf16, vectorized ----------------
__global__ __launch_bounds__(256) void cvt_x_k(const f32x4* __restrict__ src,
                                               u16x4* __restrict__ dst, int n4)
{
  int i0 = blockIdx.x * 256 + threadIdx.x;
  int stride = gridDim.x * 256;
  for (int i = i0; i < n4; i += stride) {
    f32x4 v = src[i];
    u16x4 r; r[0] = f2b(v[0]); r[1] = f2b(v[1]); r[2] = f2b(v[2]); r[3] = f2b(v[3]);
    dst[i] = r;
  }
}

// ---------------- small-tensor conversions ----------------
__global__ __launch_bounds__(256) void cvt_small_k(
    const float* __restrict__ qcw, const float* __restrict__ kcw, const float* __restrict__ vcw,
    const float* __restrict__ qcb, const float* __restrict__ kcb, const float* __restrict__ vcb,
    const float* __restrict__ ba,  const float* __restrict__ bb,
    const float* __restrict__ lnw, const float* __restrict__ lnb,
    u16* __restrict__ canon)
{
  int i = blockIdx.x * 256 + threadIdx.x;
  if (i >= 31008) return;
  float v;
  if (i < 24576) {
    const float* s = (i < 8192) ? qcw : (i < 16384) ? kcw : vcw;
    v = s[i & 8191];
  } else if (i < 30720) {
    int j = i - 24576;
    const float* s = (j < 2048) ? qcb : (j < 4096) ? kcb : vcb;
    v = s[j & 2047];
  } else if (i < 30752) {
    int j = i - 30720;
    v = (j < 16) ? ba[j] : bb[j - 16];
  } else {
    int j = i - 30752;
    v = (j < 128) ? lnw[j] : lnb[j - 128];
  }
  canon[i] = f2b(v);
}

// ---------------- batched transpose ----------------
__global__ __launch_bounds__(256) void transpose_b(const float* __restrict__ s0,
                                                   const float* __restrict__ s1,
                                                   const float* __restrict__ s2,
                                                   u16* __restrict__ dst,
                                                   int R, int C)
{
  int z = blockIdx.z;
  const float* src = (z == 0) ? s0 : (z == 1) ? s1 : s2;
  u16* d = dst + (size_t)z * R * C;
  __shared__ u16 t[32][33];
  int bx = blockIdx.x * 32;
  int by = blockIdx.y * 32;
  int lx = threadIdx.x & 31, ly = threadIdx.x >> 5;
  #pragma unroll
  for (int i = 0; i < 4; ++i) {
    int r = by + ly + i * 8, c = bx + lx;
    if (r < R && c < C) t[ly + i * 8][lx] = f2b(src[(size_t)r * C + c]);
  }
  __syncthreads();
  #pragma unroll
  for (int i = 0; i < 4; ++i) {
    int r = bx + ly + i * 8;
    int c = by + lx;
    if (r < C && c < R) d[(size_t)r * R + c] = t[lx][ly + i * 8];
  }
}

// ---------------- m97-style bf16 GEMM ----------------
#define BM 128
#define BN 128
#define BK 32

__device__ __forceinline__ void gload_lds16(const void* gp, void* lp){
  __builtin_amdgcn_global_load_lds(
      (const __attribute__((address_space(1))) void*)gp,
      (__attribute__((address_space(3))) void*)lp, 16, 0, 0);
}

__global__ __launch_bounds__(256) void gemm_bt(const u16* __restrict__ A, int lda,
                                               const u16* __restrict__ Bt, int ldb,
                                               void* __restrict__ C, int ldc,
                                               int K, int out_f32)
{
  __shared__ u16 lsA[BM * BK];
  __shared__ u16 lsB[BN * BK];
  int tid = threadIdx.x, wave = tid >> 6, lane = tid & 63;
  int m0 = blockIdx.y * BM, n0 = blockIdx.x * BN;
  int wm = (wave >> 1) * 64, wn = (wave & 1) * 64;
  int srow = lane >> 2;
  int skel = (lane & 3) * 8;
  int quad = lane >> 4, l16 = lane & 15;

  f32x4 acc[4][4];
  #pragma unroll
  for (int mi = 0; mi < 4; ++mi)
    #pragma unroll
    for (int ni = 0; ni < 4; ++ni)
      #pragma unroll
      for (int r = 0; r < 4; ++r) acc[mi][ni][r] = 0.0f;

  for (int k0 = 0; k0 < K; k0 += BK) {
    __syncthreads();
    #pragma unroll
    for (int i = 0; i < 2; ++i) {
      int row = wave * 32 + i * 16 + srow;
      gload_lds16(A  + (size_t)(m0 + row) * lda + k0 + skel,
                  lsA + (wave * 2048 + i * 1024) / 2);
      gload_lds16(Bt + (size_t)(n0 + row) * ldb + k0 + skel,
                  lsB + (wave * 2048 + i * 1024) / 2);
    }
    __syncthreads();

    const bf16x8* fA = (const bf16x8*)lsA;
    const bf16x8* fB = (const bf16x8*)lsB;
    bf16x8 af[4], bg[4];
    #pragma unroll
    for (int mi = 0; mi < 4; ++mi) af[mi] = fA[(wm + mi * 16 + l16) * 4 + quad];
    #pragma unroll
    for (int ni = 0; ni < 4; ++ni) bg[ni] = fB[(wn + ni * 16 + l16) * 4 + quad];
    #pragma unroll
    for (int mi = 0; mi < 4; ++mi)
      #pragma unroll
      for (int ni = 0; ni < 4; ++ni)
        acc[mi][ni] = MFMA16(af[mi], bg[ni], acc[mi][ni]);
  }

  #pragma unroll
  for (int mi = 0; mi < 4; ++mi)
    #pragma unroll
    for (int ni = 0; ni < 4; ++ni)
      #pragma unroll
      for (int r = 0; r < 4; ++r) {
        int m = m0 + wm + mi * 16 + quad * 4 + r;
        int n = n0 + wn + ni * 16 + l16;
        if (out_f32) ((float*)C)[(size_t)m * ldc + n] = acc[mi][ni][r];
        else         ((u16*)C)[(size_t)m * ldc + n] = f2b(acc[mi][ni][r]);
      }
}

// ---------------- alpha/beta ----------------
__global__ __launch_bounds__(256) void ab_k(const u16* __restrict__ x,
                                            const u16* __restrict__ WabT,
                                            const u16* __restrict__ ba,
                                            const u16* __restrict__ bb,
                                            float* __restrict__ ab)
{
  int j = threadIdx.x & 31, rl = threadIdx.x >> 5;
  int row = blockIdx.x * 8 + rl;
  const u16x8* xr = (const u16x8*)(x + (size_t)row * HID_);
  const u16x8* wr = (const u16x8*)(WabT + (size_t)j * HID_);
  float acc = 0.f;
  for (int k = 0; k < HID_ / 8; ++k) {
    u16x8 xv = xr[k], wv = wr[k];
    #pragma unroll
    for (int i = 0; i < 8; ++i) acc += b2f(xv[i]) * b2f(wv[i]);
  }
  float bias = (j < 16) ? b2f(ba[j]) : b2f(bb[j - 16]);
  float sg = sigm(acc + bias);
  if (j < 16) ab[(size_t)row * 16 + j] = sg;
  else        ab[(size_t)BT_ * 16 + (size_t)row * 16 + (j - 16)] = sg;
}

// ---------------- causal dwconv (KS=4) + silu ----------------
__global__ __launch_bounds__(256) void conv_silu_k(const u16* __restrict__ in,
                                                   const u16* __restrict__ cwv,
                                                   const u16* __restrict__ cbv,
                                                   u16* __restrict__ out)
{
  int idx  = blockIdx.x * 256 + threadIdx.x;
  int col8 = idx % (QKVC / 8);
  int t    = idx / (QKVC / 8);
  int col  = col8 * 8;
  int s = col >> 11;

  u16 wl[32];
  #pragma unroll
  for (int i = 0; i < 4; ++i)
    *(u16x8*)(wl + i * 8) = *(const u16x8*)(cwv + (size_t)col * KS_ + i * 8);
  u16x8 bv = *(const u16x8*)(cbv + col);

  float acc[8];
  #pragma unroll
  for (int j = 0; j < 8; ++j) acc[j] = b2f(bv[j]);

  #pragma unroll
  for (int tap = 0; tap < KS_; ++tap) {
    int tt = t - 3 + tap;
    if (tt >= 0) {
      u16x8 xv = *(const u16x8*)(in + (size_t)tt * QKVC + col);
      #pragma unroll
      for (int j = 0; j < 8; ++j) acc[j] = fmaf(b2f(xv[j]), b2f(wl[j * 4 + tap]), acc[j]);
    }
  }
  float scale = (s == 1) ? 0.08838834764831845f : 1.0f;
  u16x8 rv;
  #pragma unroll
  for (int j = 0; j < 8; ++j) {
    float a = acc[j];
    rv[j] = f2b(a * sigm(a) * scale);
  }
  *(u16x8*)(out + (size_t)t * QKVC + col) = rv;
}

// ---------------- chunked gated delta-rule scan (UT transform, MFMA) ----------------
// R6: back to 256 blocks = 4 slices x 64 chains, RS=32 (R5 showed blocks do NOT
// co-schedule: 512 blocks ran as 2 serial rounds). Structural fix instead:
//  * per-wave REDUNDANT triangular solve (4 copies, one per SIMD; latency-bound so
//    redundancy is free) into wave-PRIVATE LDS U -> no all-waves-wait-on-wave0.
//  * G / Ut / Uc MFMA fragments built on the fly from U/KQ/PL4 per wave -> shared
//    image phase (old ph4) and its barrier eliminated.
//  * barriers/chunk: 5 -> 3.  T14 reg prefetch + KT XOR swizzle kept from R5.
// All FP expressions identical to R4/R5 -> absmax fingerprint 0.04443359 expected.
__global__ __launch_bounds__(256) void chunk_scan_k(const u16* __restrict__ qkv,
                                                    const float* __restrict__ ab,
                                                    u16* __restrict__ o)
{
  __shared__ __align__(16) char smem[64512];
  u16 (*Kim)[136] = (u16(*)[136])(smem);             // [32][136]  ph1 w, ph2 r
  u16 (*Qim)[136] = (u16(*)[136])(smem + 8704);      // [32][136]  ph1 w, ph2 r
  u16 (*Sh)[136]  = (u16(*)[136])(smem + 17408);     // [32][136]  ph1 w, ph2 r
  u16 (*Sl)[136]  = (u16(*)[136])(smem + 26112);     // [32][136]
  u16 (*KT)[40]   = (u16(*)[40])(smem + 34816);      // [128][40] swizzled, ph1 w, ph3 r
  u16 (*Vim)[32]  = (u16(*)[32])(smem + 45056);      // [32][32]
  float (*KK)[33] = (float(*)[33])(smem + 47104);    // ph2 w, ph3 r
  float (*KQ)[33] = (float(*)[33])(smem + 51328);
  float (*SK0)[33]= (float(*)[33])(smem + 55552);
  float (*SQ0)[33]= (float(*)[33])(smem + 59776);
  float (*PL4)[4] = (float(*)[4])(smem + 64000);     // [32]{s_t,b_t,1/P_t,P_t}

  int bid = blockIdx.x;
  int chain = bid & 63, rblk = bid >> 6;             // rblk in [0,4)
  int b = chain >> 4, h = chain & 15;
  int tid = threadIdx.x, wv = tid >> 6, lane = tid & 63;
  int l16 = lane & 15, quad = lane >> 4, r32 = lane & 31;

  // wave-private U overlay (Qim/Sh region, free after ph2): 4 x 4224 B
  float (*Uw)[33] = (float(*)[33])(smem + 8704 + wv * 4224);

  const u16* kbase = qkv + (size_t)b * T_ * QKVC + HID_ + h * DK_;
  const u16* qbase = qkv + (size_t)b * T_ * QKVC + h * DK_;
  const u16* vbase = qkv + (size_t)b * T_ * QKVC + 2 * HID_ + h * DV_ + rblk * RS_;
  const float* abase = ab + (size_t)b * T_ * 16 + h;
  const float* bbase = abase + (size_t)BT_ * 16;
  u16* obase = o + (size_t)b * T_ * 2048 + h * DV_ + rblk * RS_;

  // persistent state: rows 0..31, wave owns cols [wv*32, wv*32+32)
  f32x4 st[2][2];
  #pragma unroll
  for (int rt = 0; rt < 2; ++rt)
    #pragma unroll
    for (int ct = 0; ct < 2; ++ct)
      #pragma unroll
      for (int r = 0; r < 4; ++r) st[rt][ct][r] = 0.f;

  int jb = tid - 64;
  u16x8 stg[6];
  float avp = 0.f;

  auto LD = [&](int c) {    // T14: issue chunk-c loads into regs, consumed next ph1
    int t0 = c * C_;
    if (wv == 0) {
      avp = (lane < 32) ? abase[(size_t)(t0 + lane) * 16]
                        : bbase[(size_t)(t0 + lane - 32) * 16];
    } else {
      #pragma unroll
      for (int it = 0; it < 6; ++it) {
        int j = jb + it * 192;
        if (j < 512) {
          int t = j >> 4, g = j & 15;
          stg[it] = *(const u16x8*)(kbase + (size_t)(t0 + t) * QKVC + g * 8);
        } else if (j < 1024) {
          int j2 = j - 512, t = j2 >> 4, g = j2 & 15;
          stg[it] = *(const u16x8*)(qbase + (size_t)(t0 + t) * QKVC + g * 8);
        } else {
          int j2 = j - 1024, t = j2 >> 2, rg = j2 & 3;
          stg[it] = *(const u16x8*)(vbase + (size_t)(t0 + t) * QKVC + rg * 8);
        }
      }
    }
  };

  LD(0);

  for (int c = 0; c < NC_; ++c) {
    int t0 = c * C_;

    // ---- ph1: state image + staging writes + gates; prefetch c+1 ----
    #pragma unroll
    for (int rt = 0; rt < 2; ++rt)
      #pragma unroll
      for (int ct = 0; ct < 2; ++ct)
        #pragma unroll
        for (int r = 0; r < 4; ++r) {
          float s = st[rt][ct][r];
          u16 hi = f2b(s);
          float lo = s - b2f(hi);
          int row = rt * 16 + quad * 4 + r;
          int col = wv * 32 + ct * 16 + l16;
          Sh[row][col] = hi;
          Sl[row][col] = f2b(lo);
        }

    if (wv == 0) {
      float av = avp;
      float p = av;
      #pragma unroll
      for (int d = 1; d < 32; d <<= 1) {
        float up = __shfl_up(p, d);
        if (lane >= d && lane < 32) p *= up;
      }
      float pm1 = __shfl_up(p, 1);
      float bt = __shfl(av, lane + 32);
      if (lane < 32) {
        if (lane == 0) pm1 = 1.f;
        f32x4 g;
        g[0] = bt * pm1; g[1] = bt; g[2] = 1.0f / p; g[3] = p;
        *(f32x4*)PL4[lane] = g;
      }
    } else {
      #pragma unroll
      for (int it = 0; it < 6; ++it) {
        int j = jb + it * 192;
        if (j < 512) {
          int t = j >> 4, g = j & 15;
          *(u16x8*)&Kim[t][g * 8] = stg[it];
          int blk = ((t >> 3) ^ (g & 3)) << 3;       // 2-bit XOR swizzle
          int tl = t & 7;
          #pragma unroll
          for (int e = 0; e < 8; ++e)
            KT[g * 8 + e][blk + tl] = stg[it][e];
        } else if (j < 1024) {
          int j2 = j - 512, t = j2 >> 4, g = j2 & 15;
          *(u16x8*)&Qim[t][g * 8] = stg[it];
        } else {
          int j2 = j - 1024, t = j2 >> 2, rg = j2 & 3;
          *(u16x8*)&Vim[t][rg * 8] = stg[it];
        }
      }
    }
    if (c + 1 < NC_) LD(c + 1);
    __syncthreads();

    // ---- ph2: KK / KQ / SK0 / SQ0 over 4 waves (disjoint tiles) ----
    {
      // tile helpers (A rows from Aarr, B rows from Kim or Sh/Sl)
      auto dotKK = [&](int mt, int nt) {
        f32x4 acc = {0.f,0.f,0.f,0.f};
        #pragma unroll
        for (int ks = 0; ks < 4; ++ks) {
          bf16x8 A = *(const bf16x8*)&Kim[mt * 16 + l16][ks * 32 + quad * 8];
          bf16x8 B = *(const bf16x8*)&Kim[nt * 16 + l16][ks * 32 + quad * 8];
          acc = MFMA16(A, B, acc);
        }
        #pragma unroll
        for (int r = 0; r < 4; ++r) KK[mt * 16 + quad * 4 + r][nt * 16 + l16] = acc[r];
      };
      auto dotKQ = [&](int mt, int nt) {
        f32x4 acc = {0.f,0.f,0.f,0.f};
        #pragma unroll
        for (int ks = 0; ks < 4; ++ks) {
          bf16x8 A = *(const bf16x8*)&Qim[mt * 16 + l16][ks * 32 + quad * 8];
          bf16x8 B = *(const bf16x8*)&Kim[nt * 16 + l16][ks * 32 + quad * 8];
          acc = MFMA16(A, B, acc);
        }
        #pragma unroll
        for (int r = 0; r < 4; ++r) KQ[mt * 16 + quad * 4 + r][nt * 16 + l16] = acc[r];
      };
      auto dotS = [&](const u16 (*Aarr)[136], int tt, int rr, float (*OUT)[33]) {
        f32x4 acc = {0.f,0.f,0.f,0.f};
        #pragma unroll
        for (int ks = 0; ks < 4; ++ks) {
          bf16x8 A  = *(const bf16x8*)&Aarr[tt * 16 + l16][ks * 32 + quad * 8];
          bf16x8 Bh = *(const bf16x8*)&Sh[rr * 16 + l16][ks * 32 + quad * 8];
          bf16x8 Bl = *(const bf16x8*)&Sl[rr * 16 + l16][ks * 32 + quad * 8];
          acc = MFMA16(A, Bh, acc);
          acc = MFMA16(A, Bl, acc);
        }
        #pragma unroll
        for (int r = 0; r < 4; ++r) OUT[tt * 16 + quad * 4 + r][rr * 16 + l16] = acc[r];
      };
      if (wv == 0)      { dotS(Kim, 0, 0, SK0); dotS(Kim, 1, 0, SK0); dotKK(0, 0); dotKK(1, 0); }
      else if (wv == 1) { dotS(Kim, 0, 1, SK0); dotS(Kim, 1, 1, SK0); dotKK(1, 1); dotKQ(0, 0); }
      else if (wv == 2) { dotS(Qim, 0, 0, SQ0); dotS(Qim, 1, 0, SQ0); dotKQ(1, 0); }
      else              { dotS(Qim, 0, 1, SQ0); dotS(Qim, 1, 1, SQ0); dotKQ(1, 1); }
    }
    __syncthreads();

    // ---- ph3: per-wave solve + on-the-fly fragments + state/output MFMAs ----
    {
      // redundant triangular solve, lane = state row (dup across halves)
      float ub[C_];
      #pragma unroll
      for (int t = 0; t < C_; ++t) {
        f32x4 g = *(const f32x4*)PL4[t];
        float u = g[0] * SK0[t][r32] - g[1] * b2f(Vim[t][r32]);
        float acc = 0.f;
        #pragma unroll
        for (int i = 0; i < t; ++i) acc = fmaf(KK[t][i], ub[i], acc);
        u = fmaf(-g[0], acc, u);
        if (lane < 32) Uw[t][lane] = u;
        ub[t] = g[2] * u;
      }

      float PL31 = PL4[31][3];

      // state update: S = P31*S + sum_i Uc[row,i] * K[i,col]
      #pragma unroll
      for (int rt = 0; rt < 2; ++rt) {
        union { u16x8 u; bf16x8 b; } ah, al;
        #pragma unroll
        for (int e = 0; e < 8; ++e) {
          int i = quad * 8 + e;
          float uv = Uw[i][rt * 16 + l16];
          float ucv = -PL31 * PL4[i][2] * uv;
          u16 hh = f2b(ucv);
          ah.u[e] = hh; al.u[e] = f2b(ucv - b2f(hh));
        }
        #pragma unroll
        for (int ct = 0; ct < 2; ++ct) {
          int col = wv * 32 + ct * 16 + l16;
          bf16x8 Bk = *(const bf16x8*)&KT[col][(quad ^ ((col >> 3) & 3)) << 3];
          f32x4 cacc;
          #pragma unroll
          for (int r = 0; r < 4; ++r) cacc[r] = PL31 * st[rt][ct][r];
          cacc = MFMA16(ah.b, Bk, cacc);
          cacc = MFMA16(al.b, Bk, cacc);
          st[rt][ct] = cacc;
        }
      }

      // outputs: wave (mt,nt) -> o[t0 + mt*16.., nt*16..]
      int mt = wv >> 1, nt = wv & 1;
      union { u16x8 u; bf16x8 b; } gh, gl, uth, utl;
      int trow = mt * 16 + l16;
      float Pt = PL4[trow][3];
      #pragma unroll
      for (int e = 0; e < 8; ++e) {
        int i = quad * 8 + e;
        float uv = Uw[i][nt * 16 + l16];
        u16 h1 = f2b(uv);
        uth.u[e] = h1; utl.u[e] = f2b(uv - b2f(h1));
        float gv = (i <= trow) ? (-Pt * PL4[i][2] * KQ[trow][i]) : 0.f;
        u16 h2 = f2b(gv);
        gh.u[e] = h2; gl.u[e] = f2b(gv - b2f(h2));
      }
      f32x4 oacc;
      #pragma unroll
      for (int r = 0; r < 4; ++r) {
        int t = mt * 16 + quad * 4 + r;
        oacc[r] = PL4[t][3] * SQ0[t][nt * 16 + l16];
      }
      oacc = MFMA16(gh.b, uth.b, oacc);
      oacc = MFMA16(gh.b, utl.b, oacc);
      oacc = MFMA16(gl.b, uth.b, oacc);
      #pragma unroll
      for (int r = 0; r < 4; ++r) {
        int t = mt * 16 + quad * 4 + r;
        obase[(size_t)(t0 + t) * 2048 + nt * 16 + l16] = f2b(oacc[r]);
      }
    }
    __syncthreads();
  }
}

// ---------------- LayerNorm(DV) * sigmoid(g) ----------------
__global__ __launch_bounds__(256) void ln_gate_k(const u16* __restrict__ o_raw,
                                                 const u16* __restrict__ g,
                                                 const u16* __restrict__ lnw,
                                                 const u16* __restrict__ lnb,
                                                 u16* __restrict__ o_ln)
{
  int gid = blockIdx.x * 4 + (threadIdx.x >> 6);
  int lane = threadIdx.x & 63;
  int row = gid >> 4, h = gid & 15;
  size_t ofs = (size_t)row * 2048 + h * 128 + lane * 2;
  unsigned int e2 = *(const unsigned int*)(o_raw + ofs);
  float ex = b2f((u16)(e2 & 0xffff)), ey = b2f((u16)(e2 >> 16));
  float s = ex + ey, ss = ex * ex + ey * ey;
  #pragma unroll
  for (int m = 1; m < 64; m <<= 1) { s += __shfl_xor(s, m); ss += __shfl_xor(ss, m); }
  float mean = s * (1.f / 128.f);
  float var  = ss * (1.f / 128.f) - mean * mean;
  float rstd = rsqrtf(fmaxf(var, 0.f) + 1e-5f);
  float w0 = b2f(lnw[lane * 2]), w1 = b2f(lnw[lane * 2 + 1]);
  float b0 = b2f(lnb[lane * 2]), b1 = b2f(lnb[lane * 2 + 1]);
  unsigned int g2 = *(const unsigned int*)(g + ofs);
  float g0 = sigm(b2f((u16)(g2 & 0xffff))), g1 = sigm(b2f((u16)(g2 >> 16)));
  float r0 = ((ex - mean) * rstd * w0 + b0) * g0;
  float r1 = ((ey - mean) * rstd * w1 + b1) * g1;
  *(unsigned int*)(o_ln + ofs) = (unsigned int)f2b(r0) | ((unsigned int)f2b(r1) << 16);
}

// ---------------- host launch ----------------
extern "C" void kernel_launch(void* const* d_in, const int* in_sizes, int n_in,
                              void* d_out, int out_size, void* d_ws, size_t ws_size,
                              hipStream_t stream)
{
  const float* x   = (const float*)d_in[0];
  const float* Wq  = (const float*)d_in[1];
  const float* Wk  = (const float*)d_in[2];
  const float* Wv  = (const float*)d_in[3];
  const float* Wa  = (const float*)d_in[4];
  const float* ba  = (const float*)d_in[5];
  const float* Wb  = (const float*)d_in[6];
  const float* bb  = (const float*)d_in[7];
  const float* Wg  = (const float*)d_in[8];
  const float* Wo  = (const float*)d_in[9];
  const float* qcw = (const float*)d_in[10];
  const float* qcb = (const float*)d_in[11];
  const float* kcw = (const float*)d_in[12];
  const float* kcb = (const float*)d_in[13];
  const float* vcw = (const float*)d_in[14];
  const float* vcb = (const float*)d_in[15];
  const float* lnw = (const float*)d_in[16];
  const float* lnb = (const float*)d_in[17];
  (void)in_sizes; (void)n_in; (void)out_size;

  char* ws = (char*)d_ws;
  size_t off = 0;
  auto alloc = [&](size_t bytes) -> void* {
    void* p = ws + off; off += (bytes + 255) & ~(size_t)255; return p;
  };
  u16* WT    = (u16*)alloc((size_t)3 * HID_ * HID_ * 2);
  u16* WabT  = (u16*)alloc((size_t)32 * HID_ * 2);
  u16* xc    = (u16*)alloc((size_t)BT_ * HID_ * 2);
  u16* canon = (u16*)alloc((size_t)31008 * 2);
  u16* preC  = (u16*)alloc((size_t)BT_ * HID_ * 2 * 2);
  u16* post  = (u16*)alloc((size_t)BT_ * QKVC * 2);
  float* abuf = (float*)alloc((size_t)2 * BT_ * 16 * 4);
  if (off > ws_size) return;

  u16* cw_c  = canon;
  u16* cb_c  = canon + 24576;
  u16* ba_c  = canon + 30720;
  u16* bb_c  = canon + 30736;
  u16* lnw_c = canon + 30752;
  u16* lnb_c = canon + 30880;

  u16* o_raw = preC;
  u16* g_raw = post;
  u16* o_ln  = post + (size_t)BT_ * HID_;
  u16* WTg   = WT;

  dim3 tb(256);

  cvt_x_k<<<dim3(4096), tb, 0, stream>>>((const f32x4*)x, (u16x4*)xc, BT_ * HID_ / 4);
  cvt_small_k<<<dim3(122), tb, 0, stream>>>(qcw, kcw, vcw, qcb, kcb, vcb, ba, bb, lnw, lnb, canon);

  transpose_b<<<dim3(64, 64, 3), tb, 0, stream>>>(Wq, Wk, Wv, WT, HID_, HID_);
  transpose_b<<<dim3(1, 64, 2), tb, 0, stream>>>(Wa, Wb, Wb, WabT, HID_, 16);

  for (int b = 0; b < B_; ++b) {
    const u16* xb = xc + (size_t)b * T_ * HID_;
    gemm_bt<<<dim3(QKVC / BN, T_ / BM), tb, 0, stream>>>(xb, HID_, WT, HID_, preC, QKVC, HID_, 0);
    conv_silu_k<<<dim3(T_ * (QKVC / 8) / 256), tb, 0, stream>>>(
        preC, cw_c, cb_c, post + (size_t)b * T_ * QKVC);
  }

  transpose_b<<<dim3(64, 64, 2), tb, 0, stream>>>(Wg, Wo, Wo, WTg, HID_, HID_);

  ab_k<<<dim3(BT_ / 8), tb, 0, stream>>>(xc, WabT, ba_c, bb_c, abuf);

  // chunked scan: 256 blocks = 4 row-slices x 64 chains (blocks do NOT co-schedule
  // beyond 1/CU on this kernel -- measured R5; grid must stay <= 256)
  chunk_scan_k<<<dim3(256), tb, 0, stream>>>(post, abuf, o_raw);

  gemm_bt<<<dim3(HID_ / BN, BT_ / BM), tb, 0, stream>>>(xc, HID_, WTg, HID_, g_raw, HID_, HID_, 0);

  ln_gate_k<<<dim3(BT_ * H_ / 4), tb, 0, stream>>>(o_raw, g_raw, lnw_c, lnb_c, o_ln);

  gemm_bt<<<dim3(HID_ / BN, BT_ / BM), tb, 0, stream>>>(o_ln, HID_,
      WT + (size_t)HID_ * HID_, HID_, d_out, HID_, HID_, 1);
}

// Round 7
// 1312.366 us; speedup vs baseline: 1.2479x; 1.0726x over previous
//
#include <hip/hip_runtime.h>
#include <stdint.h>

#define H_   16
#define DK_  128
#define DV_  128
#define HID_ 2048
#define KS_  4
#define B_   4
#define T_   2048
#define BT_  (B_*T_)     // 8192
#define QKVC (3*HID_)    // 6144
#define C_   32          // scan chunk length
#define RS_  32          // state rows per block
#define NC_  (T_/C_)     // 64 chunks

typedef unsigned short u16;
typedef short  bf16x8 __attribute__((ext_vector_type(8)));
typedef u16    u16x8  __attribute__((ext_vector_type(8)));
typedef u16    u16x4  __attribute__((ext_vector_type(4)));
typedef float  f32x4  __attribute__((ext_vector_type(4)));

__device__ __forceinline__ float b2f(u16 u){
  union { unsigned int i; float f; } v; v.i = ((unsigned int)u) << 16; return v.f;
}
__device__ __forceinline__ u16 f2b(float f){
  unsigned int x = __float_as_uint(f);
  unsigned int r = (x + 0x7FFFu + ((x >> 16) & 1u)) >> 16;
  return (u16)r;
}
__device__ __forceinline__ float sigm(float x){ return 1.0f / (1.0f + __expf(-x)); }

#define MFMA16(a,b,c) __builtin_amdgcn_mfma_f32_16x16x32_bf16((a),(b),(c),0,0,0)

// ---------------- x conversion: f32 (bf16-valued) -> bf16, vectorized ----------------
__global__ __launch_bounds__(256) void cvt_x_k(const f32x4* __restrict__ src,
                                               u16x4* __restrict__ dst, int n4)
{
  int i0 = blockIdx.x * 256 + threadIdx.x;
  int stride = gridDim.x * 256;
  for (int i = i0; i < n4; i += stride) {
    f32x4 v = src[i];
    u16x4 r; r[0] = f2b(v[0]); r[1] = f2b(v[1]); r[2] = f2b(v[2]); r[3] = f2b(v[3]);
    dst[i] = r;
  }
}

// ---------------- small-tensor conversions ----------------
__global__ __launch_bounds__(256) void cvt_small_k(
    const float* __restrict__ qcw, const float* __restrict__ kcw, const float* __restrict__ vcw,
    const float* __restrict__ qcb, const float* __restrict__ kcb, const float* __restrict__ vcb,
    const float* __restrict__ ba,  const float* __restrict__ bb,
    const float* __restrict__ lnw, const float* __restrict__ lnb,
    u16* __restrict__ canon)
{
  int i = blockIdx.x * 256 + threadIdx.x;
  if (i >= 31008) return;
  float v;
  if (i < 24576) {
    const float* s = (i < 8192) ? qcw : (i < 16384) ? kcw : vcw;
    v = s[i & 8191];
  } else if (i < 30720) {
    int j = i - 24576;
    const float* s = (j < 2048) ? qcb : (j < 4096) ? kcb : vcb;
    v = s[j & 2047];
  } else if (i < 30752) {
    int j = i - 30720;
    v = (j < 16) ? ba[j] : bb[j - 16];
  } else {
    int j = i - 30752;
    v = (j < 128) ? lnw[j] : lnb[j - 128];
  }
  canon[i] = f2b(v);
}

// ---------------- batched transpose ----------------
__global__ __launch_bounds__(256) void transpose_b(const float* __restrict__ s0,
                                                   const float* __restrict__ s1,
                                                   const float* __restrict__ s2,
                                                   u16* __restrict__ dst,
                                                   int R, int C)
{
  int z = blockIdx.z;
  const float* src = (z == 0) ? s0 : (z == 1) ? s1 : s2;
  u16* d = dst + (size_t)z * R * C;
  __shared__ u16 t[32][33];
  int bx = blockIdx.x * 32;
  int by = blockIdx.y * 32;
  int lx = threadIdx.x & 31, ly = threadIdx.x >> 5;
  #pragma unroll
  for (int i = 0; i < 4; ++i) {
    int r = by + ly + i * 8, c = bx + lx;
    if (r < R && c < C) t[ly + i * 8][lx] = f2b(src[(size_t)r * C + c]);
  }
  __syncthreads();
  #pragma unroll
  for (int i = 0; i < 4; ++i) {
    int r = bx + ly + i * 8;
    int c = by + lx;
    if (r < C && c < R) d[(size_t)r * R + c] = t[lx][ly + i * 8];
  }
}

__device__ __forceinline__ void gload_lds16(const void* gp, void* lp){
  __builtin_amdgcn_global_load_lds(
      (const __attribute__((address_space(1))) void*)gp,
      (__attribute__((address_space(3))) void*)lp, 16, 0, 0);
}

// ---------------- 256x256 double-buffered bf16 GEMM (2-phase, T3-minimum) ----------------
// C[M,N] = A[M,K] * Bt[N,K]^T.  512 threads = 8 waves (2M x 4N), per-wave 128x64 out.
// BK=64, LDS = 2 buf x (A 32KB + B 32KB) = 128KB.  Schedule per K-tile:
//   STAGE(next -> other buf); COMPUTE(cur buf); __syncthreads();
// Race-free: staging never targets the buffer being read; the barrier's implicit
// vmcnt(0) drain guarantees the staged buffer is complete before it is read.
// K-accumulation order & fragment mapping identical to the old 128^2 kernel ->
// bit-identical results (absmax fingerprint preserved).
#define GBM 256
#define GBN 256
#define GBK 64

__global__ __launch_bounds__(512, 2) void gemm256(const u16* __restrict__ A, int lda,
                                                  const u16* __restrict__ Bt, int ldb,
                                                  void* __restrict__ C, int ldc,
                                                  int K, int out_f32)
{
  __shared__ u16 lsA[2][GBM * GBK];   // 64 KB
  __shared__ u16 lsB[2][GBN * GBK];   // 64 KB
  int tid = threadIdx.x, wid = tid >> 6, lane = tid & 63;
  int l16 = lane & 15, quad = lane >> 4;
  int wr = wid >> 2, wc = wid & 3;

  // T1: bijective XCD swizzle on flattened block id (grids here are %8==0)
  int nbx = gridDim.x;
  int nwg = nbx * gridDim.y;
  int flat = blockIdx.y * nbx + blockIdx.x;
  int swzid = ((nwg & 7) == 0) ? ((flat & 7) * (nwg >> 3) + (flat >> 3)) : flat;
  int m0 = (swzid / nbx) * GBM;
  int n0 = (swzid % nbx) * GBN;

  f32x4 acc[8][4] = {};

  auto STAGE = [&](int t, int bi){
    int k0 = t * GBK;
    #pragma unroll
    for (int ld = 0; ld < 4; ++ld) {
      int slot = ld * 512 + tid;
      int row = slot >> 3, cg = slot & 7;
      int lofs = (ld * 512 + wid * 64) * 8;          // wave-uniform base (elems)
      gload_lds16(A  + (size_t)(m0 + row) * lda + k0 + cg * 8, &lsA[bi][lofs]);
      gload_lds16(Bt + (size_t)(n0 + row) * ldb + k0 + cg * 8, &lsB[bi][lofs]);
    }
  };

  STAGE(0, 0);
  __syncthreads();

  int NT = K / GBK;
  for (int t = 0; t < NT; ++t) {
    int bi = t & 1;
    if (t + 1 < NT) STAGE(t + 1, bi ^ 1);
    const u16* pA = lsA[bi];
    const u16* pB = lsB[bi];
    #pragma unroll
    for (int ks = 0; ks < 2; ++ks) {
      bf16x8 bfr[4];
      #pragma unroll
      for (int ni = 0; ni < 4; ++ni)
        bfr[ni] = *(const bf16x8*)&pB[(wc * 64 + ni * 16 + l16) * GBK + ks * 32 + quad * 8];
      #pragma unroll
      for (int mi = 0; mi < 8; ++mi) {
        bf16x8 af = *(const bf16x8*)&pA[(wr * 128 + mi * 16 + l16) * GBK + ks * 32 + quad * 8];
        #pragma unroll
        for (int ni = 0; ni < 4; ++ni)
          acc[mi][ni] = MFMA16(af, bfr[ni], acc[mi][ni]);
      }
    }
    __syncthreads();
  }

  #pragma unroll
  for (int mi = 0; mi < 8; ++mi)
    #pragma unroll
    for (int ni = 0; ni < 4; ++ni)
      #pragma unroll
      for (int r = 0; r < 4; ++r) {
        int m = m0 + wr * 128 + mi * 16 + quad * 4 + r;
        int n = n0 + wc * 64 + ni * 16 + l16;
        if (out_f32) ((float*)C)[(size_t)m * ldc + n] = acc[mi][ni][r];
        else         ((u16*)C)[(size_t)m * ldc + n] = f2b(acc[mi][ni][r]);
      }
}

// ---------------- alpha/beta ----------------
__global__ __launch_bounds__(256) void ab_k(const u16* __restrict__ x,
                                            const u16* __restrict__ WabT,
                                            const u16* __restrict__ ba,
                                            const u16* __restrict__ bb,
                                            float* __restrict__ ab)
{
  int j = threadIdx.x & 31, rl = threadIdx.x >> 5;
  int row = blockIdx.x * 8 + rl;
  const u16x8* xr = (const u16x8*)(x + (size_t)row * HID_);
  const u16x8* wr = (const u16x8*)(WabT + (size_t)j * HID_);
  float acc = 0.f;
  for (int k = 0; k < HID_ / 8; ++k) {
    u16x8 xv = xr[k], wv = wr[k];
    #pragma unroll
    for (int i = 0; i < 8; ++i) acc += b2f(xv[i]) * b2f(wv[i]);
  }
  float bias = (j < 16) ? b2f(ba[j]) : b2f(bb[j - 16]);
  float sg = sigm(acc + bias);
  if (j < 16) ab[(size_t)row * 16 + j] = sg;
  else        ab[(size_t)BT_ * 16 + (size_t)row * 16 + (j - 16)] = sg;
}

// ---------------- causal dwconv (KS=4) + silu ----------------
__global__ __launch_bounds__(256) void conv_silu_k(const u16* __restrict__ in,
                                                   const u16* __restrict__ cwv,
                                                   const u16* __restrict__ cbv,
                                                   u16* __restrict__ out)
{
  int idx  = blockIdx.x * 256 + threadIdx.x;
  int col8 = idx % (QKVC / 8);
  int t    = idx / (QKVC / 8);
  int col  = col8 * 8;
  int s = col >> 11;

  u16 wl[32];
  #pragma unroll
  for (int i = 0; i < 4; ++i)
    *(u16x8*)(wl + i * 8) = *(const u16x8*)(cwv + (size_t)col * KS_ + i * 8);
  u16x8 bv = *(const u16x8*)(cbv + col);

  float acc[8];
  #pragma unroll
  for (int j = 0; j < 8; ++j) acc[j] = b2f(bv[j]);

  #pragma unroll
  for (int tap = 0; tap < KS_; ++tap) {
    int tt = t - 3 + tap;
    if (tt >= 0) {
      u16x8 xv = *(const u16x8*)(in + (size_t)tt * QKVC + col);
      #pragma unroll
      for (int j = 0; j < 8; ++j) acc[j] = fmaf(b2f(xv[j]), b2f(wl[j * 4 + tap]), acc[j]);
    }
  }
  float scale = (s == 1) ? 0.08838834764831845f : 1.0f;
  u16x8 rv;
  #pragma unroll
  for (int j = 0; j < 8; ++j) {
    float a = acc[j];
    rv[j] = f2b(a * sigm(a) * scale);
  }
  *(u16x8*)(out + (size_t)t * QKVC + col) = rv;
}

// ---------------- chunked gated delta-rule scan (UT transform, MFMA) ----------------
// Kept exactly as R6 (validated, 502 us). Known issue for a later round: the 4x
// redundant solve quadruples scalar LDS broadcast reads on the shared per-CU LDS
// pipe (~11.6K cy/chunk) -- fix is shared solve + vectorized (b128) KK reads.
__global__ __launch_bounds__(256) void chunk_scan_k(const u16* __restrict__ qkv,
                                                    const float* __restrict__ ab,
                                                    u16* __restrict__ o)
{
  __shared__ __align__(16) char smem[64512];
  u16 (*Kim)[136] = (u16(*)[136])(smem);
  u16 (*Qim)[136] = (u16(*)[136])(smem + 8704);
  u16 (*Sh)[136]  = (u16(*)[136])(smem + 17408);
  u16 (*Sl)[136]  = (u16(*)[136])(smem + 26112);
  u16 (*KT)[40]   = (u16(*)[40])(smem + 34816);
  u16 (*Vim)[32]  = (u16(*)[32])(smem + 45056);
  float (*KK)[33] = (float(*)[33])(smem + 47104);
  float (*KQ)[33] = (float(*)[33])(smem + 51328);
  float (*SK0)[33]= (float(*)[33])(smem + 55552);
  float (*SQ0)[33]= (float(*)[33])(smem + 59776);
  float (*PL4)[4] = (float(*)[4])(smem + 64000);

  int bid = blockIdx.x;
  int chain = bid & 63, rblk = bid >> 6;
  int b = chain >> 4, h = chain & 15;
  int tid = threadIdx.x, wv = tid >> 6, lane = tid & 63;
  int l16 = lane & 15, quad = lane >> 4, r32 = lane & 31;

  float (*Uw)[33] = (float(*)[33])(smem + 8704 + wv * 4224);

  const u16* kbase = qkv + (size_t)b * T_ * QKVC + HID_ + h * DK_;
  const u16* qbase = qkv + (size_t)b * T_ * QKVC + h * DK_;
  const u16* vbase = qkv + (size_t)b * T_ * QKVC + 2 * HID_ + h * DV_ + rblk * RS_;
  const float* abase = ab + (size_t)b * T_ * 16 + h;
  const float* bbase = abase + (size_t)BT_ * 16;
  u16* obase = o + (size_t)b * T_ * 2048 + h * DV_ + rblk * RS_;

  f32x4 st[2][2];
  #pragma unroll
  for (int rt = 0; rt < 2; ++rt)
    #pragma unroll
    for (int ct = 0; ct < 2; ++ct)
      #pragma unroll
      for (int r = 0; r < 4; ++r) st[rt][ct][r] = 0.f;

  int jb = tid - 64;
  u16x8 stg[6];
  float avp = 0.f;

  auto LD = [&](int c) {
    int t0 = c * C_;
    if (wv == 0) {
      avp = (lane < 32) ? abase[(size_t)(t0 + lane) * 16]
                        : bbase[(size_t)(t0 + lane - 32) * 16];
    } else {
      #pragma unroll
      for (int it = 0; it < 6; ++it) {
        int j = jb + it * 192;
        if (j < 512) {
          int t = j >> 4, g = j & 15;
          stg[it] = *(const u16x8*)(kbase + (size_t)(t0 + t) * QKVC + g * 8);
        } else if (j < 1024) {
          int j2 = j - 512, t = j2 >> 4, g = j2 & 15;
          stg[it] = *(const u16x8*)(qbase + (size_t)(t0 + t) * QKVC + g * 8);
        } else {
          int j2 = j - 1024, t = j2 >> 2, rg = j2 & 3;
          stg[it] = *(const u16x8*)(vbase + (size_t)(t0 + t) * QKVC + rg * 8);
        }
      }
    }
  };

  LD(0);

  for (int c = 0; c < NC_; ++c) {
    int t0 = c * C_;

    #pragma unroll
    for (int rt = 0; rt < 2; ++rt)
      #pragma unroll
      for (int ct = 0; ct < 2; ++ct)
        #pragma unroll
        for (int r = 0; r < 4; ++r) {
          float s = st[rt][ct][r];
          u16 hi = f2b(s);
          float lo = s - b2f(hi);
          int row = rt * 16 + quad * 4 + r;
          int col = wv * 32 + ct * 16 + l16;
          Sh[row][col] = hi;
          Sl[row][col] = f2b(lo);
        }

    if (wv == 0) {
      float av = avp;
      float p = av;
      #pragma unroll
      for (int d = 1; d < 32; d <<= 1) {
        float up = __shfl_up(p, d);
        if (lane >= d && lane < 32) p *= up;
      }
      float pm1 = __shfl_up(p, 1);
      float bt = __shfl(av, lane + 32);
      if (lane < 32) {
        if (lane == 0) pm1 = 1.f;
        f32x4 g;
        g[0] = bt * pm1; g[1] = bt; g[2] = 1.0f / p; g[3] = p;
        *(f32x4*)PL4[lane] = g;
      }
    } else {
      #pragma unroll
      for (int it = 0; it < 6; ++it) {
        int j = jb + it * 192;
        if (j < 512) {
          int t = j >> 4, g = j & 15;
          *(u16x8*)&Kim[t][g * 8] = stg[it];
          int blk = ((t >> 3) ^ (g & 3)) << 3;
          int tl = t & 7;
          #pragma unroll
          for (int e = 0; e < 8; ++e)
            KT[g * 8 + e][blk + tl] = stg[it][e];
        } else if (j < 1024) {
          int j2 = j - 512, t = j2 >> 4, g = j2 & 15;
          *(u16x8*)&Qim[t][g * 8] = stg[it];
        } else {
          int j2 = j - 1024, t = j2 >> 2, rg = j2 & 3;
          *(u16x8*)&Vim[t][rg * 8] = stg[it];
        }
      }
    }
    if (c + 1 < NC_) LD(c + 1);
    __syncthreads();

    {
      auto dotKK = [&](int mt, int nt) {
        f32x4 acc = {0.f,0.f,0.f,0.f};
        #pragma unroll
        for (int ks = 0; ks < 4; ++ks) {
          bf16x8 A = *(const bf16x8*)&Kim[mt * 16 + l16][ks * 32 + quad * 8];
          bf16x8 B = *(const bf16x8*)&Kim[nt * 16 + l16][ks * 32 + quad * 8];
          acc = MFMA16(A, B, acc);
        }
        #pragma unroll
        for (int r = 0; r < 4; ++r) KK[mt * 16 + quad * 4 + r][nt * 16 + l16] = acc[r];
      };
      auto dotKQ = [&](int mt, int nt) {
        f32x4 acc = {0.f,0.f,0.f,0.f};
        #pragma unroll
        for (int ks = 0; ks < 4; ++ks) {
          bf16x8 A = *(const bf16x8*)&Qim[mt * 16 + l16][ks * 32 + quad * 8];
          bf16x8 B = *(const bf16x8*)&Kim[nt * 16 + l16][ks * 32 + quad * 8];
          acc = MFMA16(A, B, acc);
        }
        #pragma unroll
        for (int r = 0; r < 4; ++r) KQ[mt * 16 + quad * 4 + r][nt * 16 + l16] = acc[r];
      };
      auto dotS = [&](const u16 (*Aarr)[136], int tt, int rr, float (*OUT)[33]) {
        f32x4 acc = {0.f,0.f,0.f,0.f};
        #pragma unroll
        for (int ks = 0; ks < 4; ++ks) {
          bf16x8 A  = *(const bf16x8*)&Aarr[tt * 16 + l16][ks * 32 + quad * 8];
          bf16x8 Bh = *(const bf16x8*)&Sh[rr * 16 + l16][ks * 32 + quad * 8];
          bf16x8 Bl = *(const bf16x8*)&Sl[rr * 16 + l16][ks * 32 + quad * 8];
          acc = MFMA16(A, Bh, acc);
          acc = MFMA16(A, Bl, acc);
        }
        #pragma unroll
        for (int r = 0; r < 4; ++r) OUT[tt * 16 + quad * 4 + r][rr * 16 + l16] = acc[r];
      };
      if (wv == 0)      { dotS(Kim, 0, 0, SK0); dotS(Kim, 1, 0, SK0); dotKK(0, 0); dotKK(1, 0); }
      else if (wv == 1) { dotS(Kim, 0, 1, SK0); dotS(Kim, 1, 1, SK0); dotKK(1, 1); dotKQ(0, 0); }
      else if (wv == 2) { dotS(Qim, 0, 0, SQ0); dotS(Qim, 1, 0, SQ0); dotKQ(1, 0); }
      else              { dotS(Qim, 0, 1, SQ0); dotS(Qim, 1, 1, SQ0); dotKQ(1, 1); }
    }
    __syncthreads();

    {
      float ub[C_];
      #pragma unroll
      for (int t = 0; t < C_; ++t) {
        f32x4 g = *(const f32x4*)PL4[t];
        float u = g[0] * SK0[t][r32] - g[1] * b2f(Vim[t][r32]);
        float acc = 0.f;
        #pragma unroll
        for (int i = 0; i < t; ++i) acc = fmaf(KK[t][i], ub[i], acc);
        u = fmaf(-g[0], acc, u);
        if (lane < 32) Uw[t][lane] = u;
        ub[t] = g[2] * u;
      }

      float PL31 = PL4[31][3];

      #pragma unroll
      for (int rt = 0; rt < 2; ++rt) {
        union { u16x8 u; bf16x8 b; } ah, al;
        #pragma unroll
        for (int e = 0; e < 8; ++e) {
          int i = quad * 8 + e;
          float uv = Uw[i][rt * 16 + l16];
          float ucv = -PL31 * PL4[i][2] * uv;
          u16 hh = f2b(ucv);
          ah.u[e] = hh; al.u[e] = f2b(ucv - b2f(hh));
        }
        #pragma unroll
        for (int ct = 0; ct < 2; ++ct) {
          int col = wv * 32 + ct * 16 + l16;
          bf16x8 Bk = *(const bf16x8*)&KT[col][(quad ^ ((col >> 3) & 3)) << 3];
          f32x4 cacc;
          #pragma unroll
          for (int r = 0; r < 4; ++r) cacc[r] = PL31 * st[rt][ct][r];
          cacc = MFMA16(ah.b, Bk, cacc);
          cacc = MFMA16(al.b, Bk, cacc);
          st[rt][ct] = cacc;
        }
      }

      int mt = wv >> 1, nt = wv & 1;
      union { u16x8 u; bf16x8 b; } gh, gl, uth, utl;
      int trow = mt * 16 + l16;
      float Pt = PL4[trow][3];
      #pragma unroll
      for (int e = 0; e < 8; ++e) {
        int i = quad * 8 + e;
        float uv = Uw[i][nt * 16 + l16];
        u16 h1 = f2b(uv);
        uth.u[e] = h1; utl.u[e] = f2b(uv - b2f(h1));
        float gv = (i <= trow) ? (-Pt * PL4[i][2] * KQ[trow][i]) : 0.f;
        u16 h2 = f2b(gv);
        gh.u[e] = h2; gl.u[e] = f2b(gv - b2f(h2));
      }
      f32x4 oacc;
      #pragma unroll
      for (int r = 0; r < 4; ++r) {
        int t = mt * 16 + quad * 4 + r;
        oacc[r] = PL4[t][3] * SQ0[t][nt * 16 + l16];
      }
      oacc = MFMA16(gh.b, uth.b, oacc);
      oacc = MFMA16(gh.b, utl.b, oacc);
      oacc = MFMA16(gl.b, uth.b, oacc);
      #pragma unroll
      for (int r = 0; r < 4; ++r) {
        int t = mt * 16 + quad * 4 + r;
        obase[(size_t)(t0 + t) * 2048 + nt * 16 + l16] = f2b(oacc[r]);
      }
    }
    __syncthreads();
  }
}

// ---------------- LayerNorm(DV) * sigmoid(g) ----------------
__global__ __launch_bounds__(256) void ln_gate_k(const u16* __restrict__ o_raw,
                                                 const u16* __restrict__ g,
                                                 const u16* __restrict__ lnw,
                                                 const u16* __restrict__ lnb,
                                                 u16* __restrict__ o_ln)
{
  int gid = blockIdx.x * 4 + (threadIdx.x >> 6);
  int lane = threadIdx.x & 63;
  int row = gid >> 4, h = gid & 15;
  size_t ofs = (size_t)row * 2048 + h * 128 + lane * 2;
  unsigned int e2 = *(const unsigned int*)(o_raw + ofs);
  float ex = b2f((u16)(e2 & 0xffff)), ey = b2f((u16)(e2 >> 16));
  float s = ex + ey, ss = ex * ex + ey * ey;
  #pragma unroll
  for (int m = 1; m < 64; m <<= 1) { s += __shfl_xor(s, m); ss += __shfl_xor(ss, m); }
  float mean = s * (1.f / 128.f);
  float var  = ss * (1.f / 128.f) - mean * mean;
  float rstd = rsqrtf(fmaxf(var, 0.f) + 1e-5f);
  float w0 = b2f(lnw[lane * 2]), w1 = b2f(lnw[lane * 2 + 1]);
  float b0 = b2f(lnb[lane * 2]), b1 = b2f(lnb[lane * 2 + 1]);
  unsigned int g2 = *(const unsigned int*)(g + ofs);
  float g0 = sigm(b2f((u16)(g2 & 0xffff))), g1 = sigm(b2f((u16)(g2 >> 16)));
  float r0 = ((ex - mean) * rstd * w0 + b0) * g0;
  float r1 = ((ey - mean) * rstd * w1 + b1) * g1;
  *(unsigned int*)(o_ln + ofs) = (unsigned int)f2b(r0) | ((unsigned int)f2b(r1) << 16);
}

// ---------------- host launch ----------------
extern "C" void kernel_launch(void* const* d_in, const int* in_sizes, int n_in,
                              void* d_out, int out_size, void* d_ws, size_t ws_size,
                              hipStream_t stream)
{
  const float* x   = (const float*)d_in[0];
  const float* Wq  = (const float*)d_in[1];
  const float* Wk  = (const float*)d_in[2];
  const float* Wv  = (const float*)d_in[3];
  const float* Wa  = (const float*)d_in[4];
  const float* ba  = (const float*)d_in[5];
  const float* Wb  = (const float*)d_in[6];
  const float* bb  = (const float*)d_in[7];
  const float* Wg  = (const float*)d_in[8];
  const float* Wo  = (const float*)d_in[9];
  const float* qcw = (const float*)d_in[10];
  const float* qcb = (const float*)d_in[11];
  const float* kcw = (const float*)d_in[12];
  const float* kcb = (const float*)d_in[13];
  const float* vcw = (const float*)d_in[14];
  const float* vcb = (const float*)d_in[15];
  const float* lnw = (const float*)d_in[16];
  const float* lnb = (const float*)d_in[17];
  (void)in_sizes; (void)n_in; (void)out_size;

  char* ws = (char*)d_ws;
  size_t off = 0;
  auto alloc = [&](size_t bytes) -> void* {
    void* p = ws + off; off += (bytes + 255) & ~(size_t)255; return p;
  };
  u16* WT    = (u16*)alloc((size_t)3 * HID_ * HID_ * 2);
  u16* WabT  = (u16*)alloc((size_t)32 * HID_ * 2);
  u16* xc    = (u16*)alloc((size_t)BT_ * HID_ * 2);
  u16* canon = (u16*)alloc((size_t)31008 * 2);
  u16* post  = (u16*)alloc((size_t)BT_ * QKVC * 2);
  float* abuf = (float*)alloc((size_t)2 * BT_ * 16 * 4);
  size_t base_off = off;

  // optimistic fused layout: pre-conv buffer for ALL batches [8192][6144] bf16.
  // fallback (ws too small): per-batch pre-conv buffer [2048][6144]+o_raw region.
  size_t fused_need = base_off + (((size_t)BT_ * QKVC * 2 + 255) & ~(size_t)255);
  int fused = (fused_need <= ws_size);
  u16* preC;
  if (fused) preC = (u16*)alloc((size_t)BT_ * QKVC * 2);
  else       preC = (u16*)alloc((size_t)BT_ * HID_ * 2 * 2);
  if (off > ws_size) return;   // guard: even fallback doesn't fit

  u16* cw_c  = canon;
  u16* cb_c  = canon + 24576;
  u16* ba_c  = canon + 30720;
  u16* bb_c  = canon + 30736;
  u16* lnw_c = canon + 30752;
  u16* lnb_c = canon + 30880;

  u16* o_raw = preC;           // overlays pre-conv region after conv consumes it
  u16* g_raw = post;
  u16* o_ln  = post + (size_t)BT_ * HID_;
  u16* WTg   = WT;

  dim3 tb(256), tb5(512);

  cvt_x_k<<<dim3(4096), tb, 0, stream>>>((const f32x4*)x, (u16x4*)xc, BT_ * HID_ / 4);
  cvt_small_k<<<dim3(122), tb, 0, stream>>>(qcw, kcw, vcw, qcb, kcb, vcb, ba, bb, lnw, lnb, canon);

  transpose_b<<<dim3(64, 64, 3), tb, 0, stream>>>(Wq, Wk, Wv, WT, HID_, HID_);
  transpose_b<<<dim3(1, 64, 2), tb, 0, stream>>>(Wa, Wb, Wb, WabT, HID_, 16);

  if (fused) {
    // one M=8192 QKV projection (768 blocks, full CU coverage), then per-batch conv
    gemm256<<<dim3(QKVC / GBN, BT_ / GBM), tb5, 0, stream>>>(xc, HID_, WT, HID_, preC, QKVC, HID_, 0);
    for (int b = 0; b < B_; ++b)
      conv_silu_k<<<dim3(T_ * (QKVC / 8) / 256), tb, 0, stream>>>(
          preC + (size_t)b * T_ * QKVC, cw_c, cb_c, post + (size_t)b * T_ * QKVC);
  } else {
    for (int b = 0; b < B_; ++b) {
      const u16* xb = xc + (size_t)b * T_ * HID_;
      gemm256<<<dim3(QKVC / GBN, T_ / GBM), tb5, 0, stream>>>(xb, HID_, WT, HID_, preC, QKVC, HID_, 0);
      conv_silu_k<<<dim3(T_ * (QKVC / 8) / 256), tb, 0, stream>>>(
          preC, cw_c, cb_c, post + (size_t)b * T_ * QKVC);
    }
  }

  transpose_b<<<dim3(64, 64, 2), tb, 0, stream>>>(Wg, Wo, Wo, WTg, HID_, HID_);

  ab_k<<<dim3(BT_ / 8), tb, 0, stream>>>(xc, WabT, ba_c, bb_c, abuf);

  // chunked scan: 256 blocks = 4 row-slices x 64 chains (grid must stay <= 256; R5)
  chunk_scan_k<<<dim3(256), tb, 0, stream>>>(post, abuf, o_raw);

  gemm256<<<dim3(HID_ / GBN, BT_ / GBM), tb5, 0, stream>>>(xc, HID_, WTg, HID_, g_raw, HID_, HID_, 0);

  ln_gate_k<<<dim3(BT_ * H_ / 4), tb, 0, stream>>>(o_raw, g_raw, lnw_c, lnb_c, o_ln);

  gemm256<<<dim3(HID_ / GBN, BT_ / GBM), tb5, 0, stream>>>(o_ln, HID_,
      WT + (size_t)HID_ * HID_, HID_, d_out, HID_, HID_, 1);
}

// Round 8
// 1253.526 us; speedup vs baseline: 1.3065x; 1.0469x over previous
//
#include <hip/hip_runtime.h>
#include <stdint.h>

#define H_   16
#define DK_  128
#define DV_  128
#define HID_ 2048
#define KS_  4
#define B_   4
#define T_   2048
#define BT_  (B_*T_)     // 8192
#define QKVC (3*HID_)    // 6144
#define C_   32          // scan chunk length
#define RS_  32          // state rows per block
#define NC_  (T_/C_)     // 64 chunks

typedef unsigned short u16;
typedef short  bf16x8 __attribute__((ext_vector_type(8)));
typedef u16    u16x8  __attribute__((ext_vector_type(8)));
typedef u16    u16x4  __attribute__((ext_vector_type(4)));
typedef float  f32x4  __attribute__((ext_vector_type(4)));

__device__ __forceinline__ float b2f(u16 u){
  union { unsigned int i; float f; } v; v.i = ((unsigned int)u) << 16; return v.f;
}
__device__ __forceinline__ u16 f2b(float f){
  unsigned int x = __float_as_uint(f);
  unsigned int r = (x + 0x7FFFu + ((x >> 16) & 1u)) >> 16;
  return (u16)r;
}
__device__ __forceinline__ float sigm(float x){ return 1.0f / (1.0f + __expf(-x)); }

#define MFMA16(a,b,c) __builtin_amdgcn_mfma_f32_16x16x32_bf16((a),(b),(c),0,0,0)

// ---------------- x conversion: f32 (bf16-valued) -> bf16, vectorized ----------------
__global__ __launch_bounds__(256) void cvt_x_k(const f32x4* __restrict__ src,
                                               u16x4* __restrict__ dst, int n4)
{
  int i0 = blockIdx.x * 256 + threadIdx.x;
  int stride = gridDim.x * 256;
  for (int i = i0; i < n4; i += stride) {
    f32x4 v = src[i];
    u16x4 r; r[0] = f2b(v[0]); r[1] = f2b(v[1]); r[2] = f2b(v[2]); r[3] = f2b(v[3]);
    dst[i] = r;
  }
}

// ---------------- small-tensor conversions ----------------
__global__ __launch_bounds__(256) void cvt_small_k(
    const float* __restrict__ qcw, const float* __restrict__ kcw, const float* __restrict__ vcw,
    const float* __restrict__ qcb, const float* __restrict__ kcb, const float* __restrict__ vcb,
    const float* __restrict__ ba,  const float* __restrict__ bb,
    const float* __restrict__ lnw, const float* __restrict__ lnb,
    u16* __restrict__ canon)
{
  int i = blockIdx.x * 256 + threadIdx.x;
  if (i >= 31008) return;
  float v;
  if (i < 24576) {
    const float* s = (i < 8192) ? qcw : (i < 16384) ? kcw : vcw;
    v = s[i & 8191];
  } else if (i < 30720) {
    int j = i - 24576;
    const float* s = (j < 2048) ? qcb : (j < 4096) ? kcb : vcb;
    v = s[j & 2047];
  } else if (i < 30752) {
    int j = i - 30720;
    v = (j < 16) ? ba[j] : bb[j - 16];
  } else {
    int j = i - 30752;
    v = (j < 128) ? lnw[j] : lnb[j - 128];
  }
  canon[i] = f2b(v);
}

// ---------------- batched transpose ----------------
__global__ __launch_bounds__(256) void transpose_b(const float* __restrict__ s0,
                                                   const float* __restrict__ s1,
                                                   const float* __restrict__ s2,
                                                   u16* __restrict__ dst,
                                                   int R, int C)
{
  int z = blockIdx.z;
  const float* src = (z == 0) ? s0 : (z == 1) ? s1 : s2;
  u16* d = dst + (size_t)z * R * C;
  __shared__ u16 t[32][33];
  int bx = blockIdx.x * 32;
  int by = blockIdx.y * 32;
  int lx = threadIdx.x & 31, ly = threadIdx.x >> 5;
  #pragma unroll
  for (int i = 0; i < 4; ++i) {
    int r = by + ly + i * 8, c = bx + lx;
    if (r < R && c < C) t[ly + i * 8][lx] = f2b(src[(size_t)r * C + c]);
  }
  __syncthreads();
  #pragma unroll
  for (int i = 0; i < 4; ++i) {
    int r = bx + ly + i * 8;
    int c = by + lx;
    if (r < C && c < R) d[(size_t)r * R + c] = t[lx][ly + i * 8];
  }
}

__device__ __forceinline__ void gload_lds16(const void* gp, void* lp){
  __builtin_amdgcn_global_load_lds(
      (const __attribute__((address_space(1))) void*)gp,
      (__attribute__((address_space(3))) void*)lp, 16, 0, 0);
}

// ---------------- 256x256 double-buffered bf16 GEMM (2-phase, T3-minimum) ----------------
#define GBM 256
#define GBN 256
#define GBK 64

__global__ __launch_bounds__(512, 2) void gemm256(const u16* __restrict__ A, int lda,
                                                  const u16* __restrict__ Bt, int ldb,
                                                  void* __restrict__ C, int ldc,
                                                  int K, int out_f32)
{
  __shared__ u16 lsA[2][GBM * GBK];   // 64 KB
  __shared__ u16 lsB[2][GBN * GBK];   // 64 KB
  int tid = threadIdx.x, wid = tid >> 6, lane = tid & 63;
  int l16 = lane & 15, quad = lane >> 4;
  int wr = wid >> 2, wc = wid & 3;

  int nbx = gridDim.x;
  int nwg = nbx * gridDim.y;
  int flat = blockIdx.y * nbx + blockIdx.x;
  int swzid = ((nwg & 7) == 0) ? ((flat & 7) * (nwg >> 3) + (flat >> 3)) : flat;
  int m0 = (swzid / nbx) * GBM;
  int n0 = (swzid % nbx) * GBN;

  f32x4 acc[8][4] = {};

  auto STAGE = [&](int t, int bi){
    int k0 = t * GBK;
    #pragma unroll
    for (int ld = 0; ld < 4; ++ld) {
      int slot = ld * 512 + tid;
      int row = slot >> 3, cg = slot & 7;
      int lofs = (ld * 512 + wid * 64) * 8;          // wave-uniform base (elems)
      gload_lds16(A  + (size_t)(m0 + row) * lda + k0 + cg * 8, &lsA[bi][lofs]);
      gload_lds16(Bt + (size_t)(n0 + row) * ldb + k0 + cg * 8, &lsB[bi][lofs]);
    }
  };

  STAGE(0, 0);
  __syncthreads();

  int NT = K / GBK;
  for (int t = 0; t < NT; ++t) {
    int bi = t & 1;
    if (t + 1 < NT) STAGE(t + 1, bi ^ 1);
    const u16* pA = lsA[bi];
    const u16* pB = lsB[bi];
    #pragma unroll
    for (int ks = 0; ks < 2; ++ks) {
      bf16x8 bfr[4];
      #pragma unroll
      for (int ni = 0; ni < 4; ++ni)
        bfr[ni] = *(const bf16x8*)&pB[(wc * 64 + ni * 16 + l16) * GBK + ks * 32 + quad * 8];
      #pragma unroll
      for (int mi = 0; mi < 8; ++mi) {
        bf16x8 af = *(const bf16x8*)&pA[(wr * 128 + mi * 16 + l16) * GBK + ks * 32 + quad * 8];
        #pragma unroll
        for (int ni = 0; ni < 4; ++ni)
          acc[mi][ni] = MFMA16(af, bfr[ni], acc[mi][ni]);
      }
    }
    __syncthreads();
  }

  #pragma unroll
  for (int mi = 0; mi < 8; ++mi)
    #pragma unroll
    for (int ni = 0; ni < 4; ++ni)
      #pragma unroll
      for (int r = 0; r < 4; ++r) {
        int m = m0 + wr * 128 + mi * 16 + quad * 4 + r;
        int n = n0 + wc * 64 + ni * 16 + l16;
        if (out_f32) ((float*)C)[(size_t)m * ldc + n] = acc[mi][ni][r];
        else         ((u16*)C)[(size_t)m * ldc + n] = f2b(acc[mi][ni][r]);
      }
}

// ---------------- alpha/beta ----------------
__global__ __launch_bounds__(256) void ab_k(const u16* __restrict__ x,
                                            const u16* __restrict__ WabT,
                                            const u16* __restrict__ ba,
                                            const u16* __restrict__ bb,
                                            float* __restrict__ ab)
{
  int j = threadIdx.x & 31, rl = threadIdx.x >> 5;
  int row = blockIdx.x * 8 + rl;
  const u16x8* xr = (const u16x8*)(x + (size_t)row * HID_);
  const u16x8* wr = (const u16x8*)(WabT + (size_t)j * HID_);
  float acc = 0.f;
  for (int k = 0; k < HID_ / 8; ++k) {
    u16x8 xv = xr[k], wv = wr[k];
    #pragma unroll
    for (int i = 0; i < 8; ++i) acc += b2f(xv[i]) * b2f(wv[i]);
  }
  float bias = (j < 16) ? b2f(ba[j]) : b2f(bb[j - 16]);
  float sg = sigm(acc + bias);
  if (j < 16) ab[(size_t)row * 16 + j] = sg;
  else        ab[(size_t)BT_ * 16 + (size_t)row * 16 + (j - 16)] = sg;
}

// ---------------- causal dwconv (KS=4) + silu ----------------
__global__ __launch_bounds__(256) void conv_silu_k(const u16* __restrict__ in,
                                                   const u16* __restrict__ cwv,
                                                   const u16* __restrict__ cbv,
                                                   u16* __restrict__ out)
{
  int idx  = blockIdx.x * 256 + threadIdx.x;
  int col8 = idx % (QKVC / 8);
  int t    = idx / (QKVC / 8);
  int col  = col8 * 8;
  int s = col >> 11;

  u16 wl[32];
  #pragma unroll
  for (int i = 0; i < 4; ++i)
    *(u16x8*)(wl + i * 8) = *(const u16x8*)(cwv + (size_t)col * KS_ + i * 8);
  u16x8 bv = *(const u16x8*)(cbv + col);

  float acc[8];
  #pragma unroll
  for (int j = 0; j < 8; ++j) acc[j] = b2f(bv[j]);

  #pragma unroll
  for (int tap = 0; tap < KS_; ++tap) {
    int tt = t - 3 + tap;
    if (tt >= 0) {
      u16x8 xv = *(const u16x8*)(in + (size_t)tt * QKVC + col);
      #pragma unroll
      for (int j = 0; j < 8; ++j) acc[j] = fmaf(b2f(xv[j]), b2f(wl[j * 4 + tap]), acc[j]);
    }
  }
  float scale = (s == 1) ? 0.08838834764831845f : 1.0f;
  u16x8 rv;
  #pragma unroll
  for (int j = 0; j < 8; ++j) {
    float a = acc[j];
    rv[j] = f2b(a * sigm(a) * scale);
  }
  *(u16x8*)(out + (size_t)t * QKVC + col) = rv;
}

// ---------------- chunked gated delta-rule scan (UT transform, MFMA) ----------------
// R8 vs R6: SHARED solve (wave0 only) instead of 4x redundant -- the redundant
// solve's ~2400 scalar LDS broadcasts/chunk saturated the per-CU LDS pipe (R6
// post-mortem). KK padded to [32][36] f32 so rows are 16B-aligned -> solve reads
// KK rows as uniform ds_read_b128 (496 b32 -> ~136 b128 instrs). Identical fmaf
// sequence -> bit-identical (absmax fingerprint 0.04443359). Waves 1-3 prebuild
// their G fragments during the solve. Barriers/chunk: 4.
__global__ __launch_bounds__(256) void chunk_scan_k(const u16* __restrict__ qkv,
                                                    const float* __restrict__ ab,
                                                    u16* __restrict__ o)
{
  __shared__ __align__(16) char smem[64896];
  u16 (*Kim)[136] = (u16(*)[136])(smem);             // [32][136]
  u16 (*Qim)[136] = (u16(*)[136])(smem + 8704);      // [32][136]; U overlays after ph2
  u16 (*Sh)[136]  = (u16(*)[136])(smem + 17408);     // [32][136]
  u16 (*Sl)[136]  = (u16(*)[136])(smem + 26112);     // [32][136]
  u16 (*KT)[40]   = (u16(*)[40])(smem + 34816);      // [128][40] swizzled
  u16 (*Vim)[32]  = (u16(*)[32])(smem + 45056);      // [32][32]
  float (*KK)[36] = (float(*)[36])(smem + 47104);    // [32][36] (rows 144B, 16B-aligned)
  float (*KQ)[33] = (float(*)[33])(smem + 51712);    // [32][33]
  float (*SK0)[33]= (float(*)[33])(smem + 55936);
  float (*SQ0)[33]= (float(*)[33])(smem + 60160);
  float (*PL4)[4] = (float(*)[4])(smem + 64384);     // [32]{s_t,b_t,1/P_t,P_t}
  float (*U)[33]  = (float(*)[33])(smem + 8704);     // shared solve output (overlays Qim)

  int bid = blockIdx.x;
  int chain = bid & 63, rblk = bid >> 6;
  int b = chain >> 4, h = chain & 15;
  int tid = threadIdx.x, wv = tid >> 6, lane = tid & 63;
  int l16 = lane & 15, quad = lane >> 4;

  const u16* kbase = qkv + (size_t)b * T_ * QKVC + HID_ + h * DK_;
  const u16* qbase = qkv + (size_t)b * T_ * QKVC + h * DK_;
  const u16* vbase = qkv + (size_t)b * T_ * QKVC + 2 * HID_ + h * DV_ + rblk * RS_;
  const float* abase = ab + (size_t)b * T_ * 16 + h;
  const float* bbase = abase + (size_t)BT_ * 16;
  u16* obase = o + (size_t)b * T_ * 2048 + h * DV_ + rblk * RS_;

  f32x4 st[2][2];
  #pragma unroll
  for (int rt = 0; rt < 2; ++rt)
    #pragma unroll
    for (int ct = 0; ct < 2; ++ct)
      #pragma unroll
      for (int r = 0; r < 4; ++r) st[rt][ct][r] = 0.f;

  int jb = tid - 64;
  u16x8 stg[6];
  float avp = 0.f;

  auto LD = [&](int c) {    // T14: issue chunk-c loads into regs, consumed next ph1
    int t0 = c * C_;
    if (wv == 0) {
      avp = (lane < 32) ? abase[(size_t)(t0 + lane) * 16]
                        : bbase[(size_t)(t0 + lane - 32) * 16];
    } else {
      #pragma unroll
      for (int it = 0; it < 6; ++it) {
        int j = jb + it * 192;
        if (j < 512) {
          int t = j >> 4, g = j & 15;
          stg[it] = *(const u16x8*)(kbase + (size_t)(t0 + t) * QKVC + g * 8);
        } else if (j < 1024) {
          int j2 = j - 512, t = j2 >> 4, g = j2 & 15;
          stg[it] = *(const u16x8*)(qbase + (size_t)(t0 + t) * QKVC + g * 8);
        } else {
          int j2 = j - 1024, t = j2 >> 2, rg = j2 & 3;
          stg[it] = *(const u16x8*)(vbase + (size_t)(t0 + t) * QKVC + rg * 8);
        }
      }
    }
  };

  LD(0);

  for (int c = 0; c < NC_; ++c) {
    int t0 = c * C_;

    // ---- ph1: state image + staging writes + gates; prefetch c+1 ----
    #pragma unroll
    for (int rt = 0; rt < 2; ++rt)
      #pragma unroll
      for (int ct = 0; ct < 2; ++ct)
        #pragma unroll
        for (int r = 0; r < 4; ++r) {
          float s = st[rt][ct][r];
          u16 hi = f2b(s);
          float lo = s - b2f(hi);
          int row = rt * 16 + quad * 4 + r;
          int col = wv * 32 + ct * 16 + l16;
          Sh[row][col] = hi;
          Sl[row][col] = f2b(lo);
        }

    if (wv == 0) {
      float av = avp;
      float p = av;
      #pragma unroll
      for (int d = 1; d < 32; d <<= 1) {
        float up = __shfl_up(p, d);
        if (lane >= d && lane < 32) p *= up;
      }
      float pm1 = __shfl_up(p, 1);
      float bt = __shfl(av, lane + 32);
      if (lane < 32) {
        if (lane == 0) pm1 = 1.f;
        f32x4 g;
        g[0] = bt * pm1; g[1] = bt; g[2] = 1.0f / p; g[3] = p;
        *(f32x4*)PL4[lane] = g;
      }
    } else {
      #pragma unroll
      for (int it = 0; it < 6; ++it) {
        int j = jb + it * 192;
        if (j < 512) {
          int t = j >> 4, g = j & 15;
          *(u16x8*)&Kim[t][g * 8] = stg[it];
          int blk = ((t >> 3) ^ (g & 3)) << 3;
          int tl = t & 7;
          #pragma unroll
          for (int e = 0; e < 8; ++e)
            KT[g * 8 + e][blk + tl] = stg[it][e];
        } else if (j < 1024) {
          int j2 = j - 512, t = j2 >> 4, g = j2 & 15;
          *(u16x8*)&Qim[t][g * 8] = stg[it];
        } else {
          int j2 = j - 1024, t = j2 >> 2, rg = j2 & 3;
          *(u16x8*)&Vim[t][rg * 8] = stg[it];
        }
      }
    }
    if (c + 1 < NC_) LD(c + 1);
    __syncthreads();

    // ---- ph2: KK / KQ / SK0 / SQ0 over 4 waves (disjoint tiles) ----
    {
      auto dotKK = [&](int mt, int nt) {
        f32x4 acc = {0.f,0.f,0.f,0.f};
        #pragma unroll
        for (int ks = 0; ks < 4; ++ks) {
          bf16x8 A = *(const bf16x8*)&Kim[mt * 16 + l16][ks * 32 + quad * 8];
          bf16x8 B = *(const bf16x8*)&Kim[nt * 16 + l16][ks * 32 + quad * 8];
          acc = MFMA16(A, B, acc);
        }
        #pragma unroll
        for (int r = 0; r < 4; ++r) KK[mt * 16 + quad * 4 + r][nt * 16 + l16] = acc[r];
      };
      auto dotKQ = [&](int mt, int nt) {
        f32x4 acc = {0.f,0.f,0.f,0.f};
        #pragma unroll
        for (int ks = 0; ks < 4; ++ks) {
          bf16x8 A = *(const bf16x8*)&Qim[mt * 16 + l16][ks * 32 + quad * 8];
          bf16x8 B = *(const bf16x8*)&Kim[nt * 16 + l16][ks * 32 + quad * 8];
          acc = MFMA16(A, B, acc);
        }
        #pragma unroll
        for (int r = 0; r < 4; ++r) KQ[mt * 16 + quad * 4 + r][nt * 16 + l16] = acc[r];
      };
      auto dotS = [&](const u16 (*Aarr)[136], int tt, int rr, float (*OUT)[33]) {
        f32x4 acc = {0.f,0.f,0.f,0.f};
        #pragma unroll
        for (int ks = 0; ks < 4; ++ks) {
          bf16x8 A  = *(const bf16x8*)&Aarr[tt * 16 + l16][ks * 32 + quad * 8];
          bf16x8 Bh = *(const bf16x8*)&Sh[rr * 16 + l16][ks * 32 + quad * 8];
          bf16x8 Bl = *(const bf16x8*)&Sl[rr * 16 + l16][ks * 32 + quad * 8];
          acc = MFMA16(A, Bh, acc);
          acc = MFMA16(A, Bl, acc);
        }
        #pragma unroll
        for (int r = 0; r < 4; ++r) OUT[tt * 16 + quad * 4 + r][rr * 16 + l16] = acc[r];
      };
      if (wv == 0)      { dotS(Kim, 0, 0, SK0); dotS(Kim, 1, 0, SK0); dotKK(0, 0); dotKK(1, 0); }
      else if (wv == 1) { dotS(Kim, 0, 1, SK0); dotS(Kim, 1, 1, SK0); dotKK(1, 1); dotKQ(0, 0); }
      else if (wv == 2) { dotS(Qim, 0, 0, SQ0); dotS(Qim, 1, 0, SQ0); dotKQ(1, 0); }
      else              { dotS(Qim, 0, 1, SQ0); dotS(Qim, 1, 1, SQ0); dotKQ(1, 1); }
    }
    __syncthreads();

    // ---- ph3a: wave0 shared solve (vectorized KK reads) || waves1-3 G frags ----
    union { u16x8 u; bf16x8 b; } gh, gl;
    if (wv == 0) {
      if (lane < 32) {
        float ub[C_];
        #pragma unroll
        for (int t = 0; t < C_; ++t) {
          f32x4 g = *(const f32x4*)PL4[t];
          float u = g[0] * SK0[t][lane] - g[1] * b2f(Vim[t][lane]);
          float acc = 0.f;
          #pragma unroll
          for (int i4 = 0; i4 < t / 4; ++i4) {
            f32x4 kk = *(const f32x4*)&KK[t][i4 * 4];   // uniform b128 broadcast
            acc = fmaf(kk[0], ub[i4 * 4 + 0], acc);
            acc = fmaf(kk[1], ub[i4 * 4 + 1], acc);
            acc = fmaf(kk[2], ub[i4 * 4 + 2], acc);
            acc = fmaf(kk[3], ub[i4 * 4 + 3], acc);
          }
          #pragma unroll
          for (int i = (t / 4) * 4; i < t; ++i)
            acc = fmaf(KK[t][i], ub[i], acc);
          u = fmaf(-g[0], acc, u);
          U[t][lane] = u;
          ub[t] = g[2] * u;
        }
      }
    } else {
      int mt = wv >> 1, nt = wv & 1; (void)nt;
      int trow = mt * 16 + l16;
      float Pt = PL4[trow][3];
      #pragma unroll
      for (int e = 0; e < 8; ++e) {
        int i = quad * 8 + e;
        float gv = (i <= trow) ? (-Pt * PL4[i][2] * KQ[trow][i]) : 0.f;
        u16 h2 = f2b(gv);
        gh.u[e] = h2; gl.u[e] = f2b(gv - b2f(h2));
      }
    }
    __syncthreads();

    // ---- ph3b: all waves build u-frags from shared U; state + output MFMAs ----
    {
      float PL31 = PL4[31][3];

      #pragma unroll
      for (int rt = 0; rt < 2; ++rt) {
        union { u16x8 u; bf16x8 b; } ah, al;
        #pragma unroll
        for (int e = 0; e < 8; ++e) {
          int i = quad * 8 + e;
          float uv = U[i][rt * 16 + l16];
          float ucv = -PL31 * PL4[i][2] * uv;
          u16 hh = f2b(ucv);
          ah.u[e] = hh; al.u[e] = f2b(ucv - b2f(hh));
        }
        #pragma unroll
        for (int ct = 0; ct < 2; ++ct) {
          int col = wv * 32 + ct * 16 + l16;
          bf16x8 Bk = *(const bf16x8*)&KT[col][(quad ^ ((col >> 3) & 3)) << 3];
          f32x4 cacc;
          #pragma unroll
          for (int r = 0; r < 4; ++r) cacc[r] = PL31 * st[rt][ct][r];
          cacc = MFMA16(ah.b, Bk, cacc);
          cacc = MFMA16(al.b, Bk, cacc);
          st[rt][ct] = cacc;
        }
      }

      int mt = wv >> 1, nt = wv & 1;
      if (wv == 0) {                       // wave0 builds its G frags now
        int trow = mt * 16 + l16;
        float Pt = PL4[trow][3];
        #pragma unroll
        for (int e = 0; e < 8; ++e) {
          int i = quad * 8 + e;
          float gv = (i <= trow) ? (-Pt * PL4[i][2] * KQ[trow][i]) : 0.f;
          u16 h2 = f2b(gv);
          gh.u[e] = h2; gl.u[e] = f2b(gv - b2f(h2));
        }
      }
      union { u16x8 u; bf16x8 b; } uth, utl;
      #pragma unroll
      for (int e = 0; e < 8; ++e) {
        int i = quad * 8 + e;
        float uv = U[i][nt * 16 + l16];
        u16 h1 = f2b(uv);
        uth.u[e] = h1; utl.u[e] = f2b(uv - b2f(h1));
      }
      f32x4 oacc;
      #pragma unroll
      for (int r = 0; r < 4; ++r) {
        int t = mt * 16 + quad * 4 + r;
        oacc[r] = PL4[t][3] * SQ0[t][nt * 16 + l16];
      }
      oacc = MFMA16(gh.b, uth.b, oacc);
      oacc = MFMA16(gh.b, utl.b, oacc);
      oacc = MFMA16(gl.b, uth.b, oacc);
      #pragma unroll
      for (int r = 0; r < 4; ++r) {
        int t = mt * 16 + quad * 4 + r;
        obase[(size_t)(t0 + t) * 2048 + nt * 16 + l16] = f2b(oacc[r]);
      }
    }
    __syncthreads();
  }
}

// ---------------- LayerNorm(DV) * sigmoid(g) ----------------
__global__ __launch_bounds__(256) void ln_gate_k(const u16* __restrict__ o_raw,
                                                 const u16* __restrict__ g,
                                                 const u16* __restrict__ lnw,
                                                 const u16* __restrict__ lnb,
                                                 u16* __restrict__ o_ln)
{
  int gid = blockIdx.x * 4 + (threadIdx.x >> 6);
  int lane = threadIdx.x & 63;
  int row = gid >> 4, h = gid & 15;
  size_t ofs = (size_t)row * 2048 + h * 128 + lane * 2;
  unsigned int e2 = *(const unsigned int*)(o_raw + ofs);
  float ex = b2f((u16)(e2 & 0xffff)), ey = b2f((u16)(e2 >> 16));
  float s = ex + ey, ss = ex * ex + ey * ey;
  #pragma unroll
  for (int m = 1; m < 64; m <<= 1) { s += __shfl_xor(s, m); ss += __shfl_xor(ss, m); }
  float mean = s * (1.f / 128.f);
  float var  = ss * (1.f / 128.f) - mean * mean;
  float rstd = rsqrtf(fmaxf(var, 0.f) + 1e-5f);
  float w0 = b2f(lnw[lane * 2]), w1 = b2f(lnw[lane * 2 + 1]);
  float b0 = b2f(lnb[lane * 2]), b1 = b2f(lnb[lane * 2 + 1]);
  unsigned int g2 = *(const unsigned int*)(g + ofs);
  float g0 = sigm(b2f((u16)(g2 & 0xffff))), g1 = sigm(b2f((u16)(g2 >> 16)));
  float r0 = ((ex - mean) * rstd * w0 + b0) * g0;
  float r1 = ((ey - mean) * rstd * w1 + b1) * g1;
  *(unsigned int*)(o_ln + ofs) = (unsigned int)f2b(r0) | ((unsigned int)f2b(r1) << 16);
}

// ---------------- host launch ----------------
extern "C" void kernel_launch(void* const* d_in, const int* in_sizes, int n_in,
                              void* d_out, int out_size, void* d_ws, size_t ws_size,
                              hipStream_t stream)
{
  const float* x   = (const float*)d_in[0];
  const float* Wq  = (const float*)d_in[1];
  const float* Wk  = (const float*)d_in[2];
  const float* Wv  = (const float*)d_in[3];
  const float* Wa  = (const float*)d_in[4];
  const float* ba  = (const float*)d_in[5];
  const float* Wb  = (const float*)d_in[6];
  const float* bb  = (const float*)d_in[7];
  const float* Wg  = (const float*)d_in[8];
  const float* Wo  = (const float*)d_in[9];
  const float* qcw = (const float*)d_in[10];
  const float* qcb = (const float*)d_in[11];
  const float* kcw = (const float*)d_in[12];
  const float* kcb = (const float*)d_in[13];
  const float* vcw = (const float*)d_in[14];
  const float* vcb = (const float*)d_in[15];
  const float* lnw = (const float*)d_in[16];
  const float* lnb = (const float*)d_in[17];
  (void)in_sizes; (void)n_in; (void)out_size;

  char* ws = (char*)d_ws;
  size_t off = 0;
  auto alloc = [&](size_t bytes) -> void* {
    void* p = ws + off; off += (bytes + 255) & ~(size_t)255; return p;
  };
  u16* WT    = (u16*)alloc((size_t)3 * HID_ * HID_ * 2);
  u16* WabT  = (u16*)alloc((size_t)32 * HID_ * 2);
  u16* xc    = (u16*)alloc((size_t)BT_ * HID_ * 2);
  u16* canon = (u16*)alloc((size_t)31008 * 2);
  u16* post  = (u16*)alloc((size_t)BT_ * QKVC * 2);
  float* abuf = (float*)alloc((size_t)2 * BT_ * 16 * 4);
  size_t base_off = off;

  size_t fused_need = base_off + (((size_t)BT_ * QKVC * 2 + 255) & ~(size_t)255);
  int fused = (fused_need <= ws_size);
  u16* preC;
  if (fused) preC = (u16*)alloc((size_t)BT_ * QKVC * 2);
  else       preC = (u16*)alloc((size_t)BT_ * HID_ * 2 * 2);
  if (off > ws_size) return;

  u16* cw_c  = canon;
  u16* cb_c  = canon + 24576;
  u16* ba_c  = canon + 30720;
  u16* bb_c  = canon + 30736;
  u16* lnw_c = canon + 30752;
  u16* lnb_c = canon + 30880;

  u16* o_raw = preC;
  u16* g_raw = post;
  u16* o_ln  = post + (size_t)BT_ * HID_;
  u16* WTg   = WT;

  dim3 tb(256), tb5(512);

  cvt_x_k<<<dim3(4096), tb, 0, stream>>>((const f32x4*)x, (u16x4*)xc, BT_ * HID_ / 4);
  cvt_small_k<<<dim3(122), tb, 0, stream>>>(qcw, kcw, vcw, qcb, kcb, vcb, ba, bb, lnw, lnb, canon);

  transpose_b<<<dim3(64, 64, 3), tb, 0, stream>>>(Wq, Wk, Wv, WT, HID_, HID_);
  transpose_b<<<dim3(1, 64, 2), tb, 0, stream>>>(Wa, Wb, Wb, WabT, HID_, 16);

  if (fused) {
    gemm256<<<dim3(QKVC / GBN, BT_ / GBM), tb5, 0, stream>>>(xc, HID_, WT, HID_, preC, QKVC, HID_, 0);
    for (int b = 0; b < B_; ++b)
      conv_silu_k<<<dim3(T_ * (QKVC / 8) / 256), tb, 0, stream>>>(
          preC + (size_t)b * T_ * QKVC, cw_c, cb_c, post + (size_t)b * T_ * QKVC);
  } else {
    for (int b = 0; b < B_; ++b) {
      const u16* xb = xc + (size_t)b * T_ * HID_;
      gemm256<<<dim3(QKVC / GBN, T_ / GBM), tb5, 0, stream>>>(xb, HID_, WT, HID_, preC, QKVC, HID_, 0);
      conv_silu_k<<<dim3(T_ * (QKVC / 8) / 256), tb, 0, stream>>>(
          preC, cw_c, cb_c, post + (size_t)b * T_ * QKVC);
    }
  }

  transpose_b<<<dim3(64, 64, 2), tb, 0, stream>>>(Wg, Wo, Wo, WTg, HID_, HID_);

  ab_k<<<dim3(BT_ / 8), tb, 0, stream>>>(xc, WabT, ba_c, bb_c, abuf);

  // chunked scan: 256 blocks = 4 row-slices x 64 chains (grid must stay <= 256; R5)
  chunk_scan_k<<<dim3(256), tb, 0, stream>>>(post, abuf, o_raw);

  gemm256<<<dim3(HID_ / GBN, BT_ / GBM), tb5, 0, stream>>>(xc, HID_, WTg, HID_, g_raw, HID_, HID_, 0);

  ln_gate_k<<<dim3(BT_ * H_ / 4), tb, 0, stream>>>(o_raw, g_raw, lnw_c, lnb_c, o_ln);

  gemm256<<<dim3(HID_ / GBN, BT_ / GBM), tb5, 0, stream>>>(o_ln, HID_,
      WT + (size_t)HID_ * HID_, HID_, d_out, HID_, HID_, 1);
}

// Round 9
// 1233.462 us; speedup vs baseline: 1.3278x; 1.0163x over previous
//
#include <hip/hip_runtime.h>
#include <stdint.h>

#define H_   16
#define DK_  128
#define DV_  128
#define HID_ 2048
#define KS_  4
#define B_   4
#define T_   2048
#define BT_  (B_*T_)     // 8192
#define QKVC (3*HID_)    // 6144
#define C_   32          // scan chunk length
#define RS_  32          // state rows per block
#define NC_  (T_/C_)     // 64 chunks

typedef unsigned short u16;
typedef short  bf16x8 __attribute__((ext_vector_type(8)));
typedef u16    u16x8  __attribute__((ext_vector_type(8)));
typedef u16    u16x4  __attribute__((ext_vector_type(4)));
typedef float  f32x4  __attribute__((ext_vector_type(4)));

__device__ __forceinline__ float b2f(u16 u){
  union { unsigned int i; float f; } v; v.i = ((unsigned int)u) << 16; return v.f;
}
__device__ __forceinline__ u16 f2b(float f){
  unsigned int x = __float_as_uint(f);
  unsigned int r = (x + 0x7FFFu + ((x >> 16) & 1u)) >> 16;
  return (u16)r;
}
__device__ __forceinline__ float sigm(float x){ return 1.0f / (1.0f + __expf(-x)); }

#define MFMA16(a,b,c) __builtin_amdgcn_mfma_f32_16x16x32_bf16((a),(b),(c),0,0,0)

// ---------------- x conversion: f32 (bf16-valued) -> bf16, vectorized ----------------
__global__ __launch_bounds__(256) void cvt_x_k(const f32x4* __restrict__ src,
                                               u16x4* __restrict__ dst, int n4)
{
  int i0 = blockIdx.x * 256 + threadIdx.x;
  int stride = gridDim.x * 256;
  for (int i = i0; i < n4; i += stride) {
    f32x4 v = src[i];
    u16x4 r; r[0] = f2b(v[0]); r[1] = f2b(v[1]); r[2] = f2b(v[2]); r[3] = f2b(v[3]);
    dst[i] = r;
  }
}

// ---------------- small-tensor conversions ----------------
__global__ __launch_bounds__(256) void cvt_small_k(
    const float* __restrict__ qcw, const float* __restrict__ kcw, const float* __restrict__ vcw,
    const float* __restrict__ qcb, const float* __restrict__ kcb, const float* __restrict__ vcb,
    const float* __restrict__ ba,  const float* __restrict__ bb,
    const float* __restrict__ lnw, const float* __restrict__ lnb,
    u16* __restrict__ canon)
{
  int i = blockIdx.x * 256 + threadIdx.x;
  if (i >= 31008) return;
  float v;
  if (i < 24576) {
    const float* s = (i < 8192) ? qcw : (i < 16384) ? kcw : vcw;
    v = s[i & 8191];
  } else if (i < 30720) {
    int j = i - 24576;
    const float* s = (j < 2048) ? qcb : (j < 4096) ? kcb : vcb;
    v = s[j & 2047];
  } else if (i < 30752) {
    int j = i - 30720;
    v = (j < 16) ? ba[j] : bb[j - 16];
  } else {
    int j = i - 30752;
    v = (j < 128) ? lnw[j] : lnb[j - 128];
  }
  canon[i] = f2b(v);
}

// ---------------- batched transpose ----------------
__global__ __launch_bounds__(256) void transpose_b(const float* __restrict__ s0,
                                                   const float* __restrict__ s1,
                                                   const float* __restrict__ s2,
                                                   u16* __restrict__ dst,
                                                   int R, int C)
{
  int z = blockIdx.z;
  const float* src = (z == 0) ? s0 : (z == 1) ? s1 : s2;
  u16* d = dst + (size_t)z * R * C;
  __shared__ u16 t[32][33];
  int bx = blockIdx.x * 32;
  int by = blockIdx.y * 32;
  int lx = threadIdx.x & 31, ly = threadIdx.x >> 5;
  #pragma unroll
  for (int i = 0; i < 4; ++i) {
    int r = by + ly + i * 8, c = bx + lx;
    if (r < R && c < C) t[ly + i * 8][lx] = f2b(src[(size_t)r * C + c]);
  }
  __syncthreads();
  #pragma unroll
  for (int i = 0; i < 4; ++i) {
    int r = bx + ly + i * 8;
    int c = by + lx;
    if (r < C && c < R) d[(size_t)r * R + c] = t[lx][ly + i * 8];
  }
}

__device__ __forceinline__ void gload_lds16(const void* gp, void* lp){
  __builtin_amdgcn_global_load_lds(
      (const __attribute__((address_space(1))) void*)gp,
      (__attribute__((address_space(3))) void*)lp, 16, 0, 0);
}

// ---------------- 256x256 double-buffered bf16 GEMM (2-phase, T3-minimum) ----------------
#define GBM 256
#define GBN 256
#define GBK 64

__global__ __launch_bounds__(512, 2) void gemm256(const u16* __restrict__ A, int lda,
                                                  const u16* __restrict__ Bt, int ldb,
                                                  void* __restrict__ C, int ldc,
                                                  int K, int out_f32)
{
  __shared__ u16 lsA[2][GBM * GBK];   // 64 KB
  __shared__ u16 lsB[2][GBN * GBK];   // 64 KB
  int tid = threadIdx.x, wid = tid >> 6, lane = tid & 63;
  int l16 = lane & 15, quad = lane >> 4;
  int wr = wid >> 2, wc = wid & 3;

  int nbx = gridDim.x;
  int nwg = nbx * gridDim.y;
  int flat = blockIdx.y * nbx + blockIdx.x;
  int swzid = ((nwg & 7) == 0) ? ((flat & 7) * (nwg >> 3) + (flat >> 3)) : flat;
  int m0 = (swzid / nbx) * GBM;
  int n0 = (swzid % nbx) * GBN;

  f32x4 acc[8][4] = {};

  auto STAGE = [&](int t, int bi){
    int k0 = t * GBK;
    #pragma unroll
    for (int ld = 0; ld < 4; ++ld) {
      int slot = ld * 512 + tid;
      int row = slot >> 3, cg = slot & 7;
      int lofs = (ld * 512 + wid * 64) * 8;          // wave-uniform base (elems)
      gload_lds16(A  + (size_t)(m0 + row) * lda + k0 + cg * 8, &lsA[bi][lofs]);
      gload_lds16(Bt + (size_t)(n0 + row) * ldb + k0 + cg * 8, &lsB[bi][lofs]);
    }
  };

  STAGE(0, 0);
  __syncthreads();

  int NT = K / GBK;
  for (int t = 0; t < NT; ++t) {
    int bi = t & 1;
    if (t + 1 < NT) STAGE(t + 1, bi ^ 1);
    const u16* pA = lsA[bi];
    const u16* pB = lsB[bi];
    #pragma unroll
    for (int ks = 0; ks < 2; ++ks) {
      bf16x8 bfr[4];
      #pragma unroll
      for (int ni = 0; ni < 4; ++ni)
        bfr[ni] = *(const bf16x8*)&pB[(wc * 64 + ni * 16 + l16) * GBK + ks * 32 + quad * 8];
      #pragma unroll
      for (int mi = 0; mi < 8; ++mi) {
        bf16x8 af = *(const bf16x8*)&pA[(wr * 128 + mi * 16 + l16) * GBK + ks * 32 + quad * 8];
        #pragma unroll
        for (int ni = 0; ni < 4; ++ni)
          acc[mi][ni] = MFMA16(af, bfr[ni], acc[mi][ni]);
      }
    }
    __syncthreads();
  }

  #pragma unroll
  for (int mi = 0; mi < 8; ++mi)
    #pragma unroll
    for (int ni = 0; ni < 4; ++ni)
      #pragma unroll
      for (int r = 0; r < 4; ++r) {
        int m = m0 + wr * 128 + mi * 16 + quad * 4 + r;
        int n = n0 + wc * 64 + ni * 16 + l16;
        if (out_f32) ((float*)C)[(size_t)m * ldc + n] = acc[mi][ni][r];
        else         ((u16*)C)[(size_t)m * ldc + n] = f2b(acc[mi][ni][r]);
      }
}

// ---------------- alpha/beta ----------------
__global__ __launch_bounds__(256) void ab_k(const u16* __restrict__ x,
                                            const u16* __restrict__ WabT,
                                            const u16* __restrict__ ba,
                                            const u16* __restrict__ bb,
                                            float* __restrict__ ab)
{
  int j = threadIdx.x & 31, rl = threadIdx.x >> 5;
  int row = blockIdx.x * 8 + rl;
  const u16x8* xr = (const u16x8*)(x + (size_t)row * HID_);
  const u16x8* wr = (const u16x8*)(WabT + (size_t)j * HID_);
  float acc = 0.f;
  for (int k = 0; k < HID_ / 8; ++k) {
    u16x8 xv = xr[k], wv = wr[k];
    #pragma unroll
    for (int i = 0; i < 8; ++i) acc += b2f(xv[i]) * b2f(wv[i]);
  }
  float bias = (j < 16) ? b2f(ba[j]) : b2f(bb[j - 16]);
  float sg = sigm(acc + bias);
  if (j < 16) ab[(size_t)row * 16 + j] = sg;
  else        ab[(size_t)BT_ * 16 + (size_t)row * 16 + (j - 16)] = sg;
}

// ---------------- causal dwconv (KS=4) + silu ----------------
__global__ __launch_bounds__(256) void conv_silu_k(const u16* __restrict__ in,
                                                   const u16* __restrict__ cwv,
                                                   const u16* __restrict__ cbv,
                                                   u16* __restrict__ out)
{
  int idx  = blockIdx.x * 256 + threadIdx.x;
  int col8 = idx % (QKVC / 8);
  int t    = idx / (QKVC / 8);
  int col  = col8 * 8;
  int s = col >> 11;

  u16 wl[32];
  #pragma unroll
  for (int i = 0; i < 4; ++i)
    *(u16x8*)(wl + i * 8) = *(const u16x8*)(cwv + (size_t)col * KS_ + i * 8);
  u16x8 bv = *(const u16x8*)(cbv + col);

  float acc[8];
  #pragma unroll
  for (int j = 0; j < 8; ++j) acc[j] = b2f(bv[j]);

  #pragma unroll
  for (int tap = 0; tap < KS_; ++tap) {
    int tt = t - 3 + tap;
    if (tt >= 0) {
      u16x8 xv = *(const u16x8*)(in + (size_t)tt * QKVC + col);
      #pragma unroll
      for (int j = 0; j < 8; ++j) acc[j] = fmaf(b2f(xv[j]), b2f(wl[j * 4 + tap]), acc[j]);
    }
  }
  float scale = (s == 1) ? 0.08838834764831845f : 1.0f;
  u16x8 rv;
  #pragma unroll
  for (int j = 0; j < 8; ++j) {
    float a = acc[j];
    rv[j] = f2b(a * sigm(a) * scale);
  }
  *(u16x8*)(out + (size_t)t * QKVC + col) = rv;
}

// ---------------- chunked gated delta-rule scan (UT transform, MFMA) ----------------
// R9 vs R8: 512-thread block (8 waves, 2 waves/SIMD). R5 showed a second BLOCK never
// co-schedules on a CU; R8's 4-wave block left 11.7% occupancy with every phase's
// latency exposed. 8 waves halve each parallel phase: state cols 16/wave, ph2's 14
// score-tile jobs spread <=2/wave, staging over 7 waves, output tiles on waves 4-7
// (G frags prebuilt during wave0's serial solve). FP expressions unchanged ->
// absmax fingerprint 0.04443359 expected.
__global__ __launch_bounds__(512) void chunk_scan_k(const u16* __restrict__ qkv,
                                                    const float* __restrict__ ab,
                                                    u16* __restrict__ o)
{
  __shared__ __align__(16) char smem[64896];
  u16 (*Kim)[136] = (u16(*)[136])(smem);             // [32][136]
  u16 (*Qim)[136] = (u16(*)[136])(smem + 8704);      // [32][136]; U overlays after ph2
  u16 (*Sh)[136]  = (u16(*)[136])(smem + 17408);     // [32][136]
  u16 (*Sl)[136]  = (u16(*)[136])(smem + 26112);     // [32][136]
  u16 (*KT)[40]   = (u16(*)[40])(smem + 34816);      // [128][40] swizzled
  u16 (*Vim)[32]  = (u16(*)[32])(smem + 45056);      // [32][32]
  float (*KK)[36] = (float(*)[36])(smem + 47104);    // [32][36] (rows 144B, 16B-aligned)
  float (*KQ)[33] = (float(*)[33])(smem + 51712);    // [32][33]
  float (*SK0)[33]= (float(*)[33])(smem + 55936);
  float (*SQ0)[33]= (float(*)[33])(smem + 60160);
  float (*PL4)[4] = (float(*)[4])(smem + 64384);     // [32]{s_t,b_t,1/P_t,P_t}
  float (*U)[33]  = (float(*)[33])(smem + 8704);     // shared solve output (overlays Qim)

  int bid = blockIdx.x;
  int chain = bid & 63, rblk = bid >> 6;
  int b = chain >> 4, h = chain & 15;
  int tid = threadIdx.x, wv = tid >> 6, lane = tid & 63;
  int l16 = lane & 15, quad = lane >> 4;

  const u16* kbase = qkv + (size_t)b * T_ * QKVC + HID_ + h * DK_;
  const u16* qbase = qkv + (size_t)b * T_ * QKVC + h * DK_;
  const u16* vbase = qkv + (size_t)b * T_ * QKVC + 2 * HID_ + h * DV_ + rblk * RS_;
  const float* abase = ab + (size_t)b * T_ * 16 + h;
  const float* bbase = abase + (size_t)BT_ * 16;
  u16* obase = o + (size_t)b * T_ * 2048 + h * DV_ + rblk * RS_;

  // persistent state: rows 0..31, wave owns cols [wv*16, wv*16+16)
  f32x4 st[2];
  #pragma unroll
  for (int rt = 0; rt < 2; ++rt)
    #pragma unroll
    for (int r = 0; r < 4; ++r) st[rt][r] = 0.f;

  int jb = tid - 64;        // staging index for waves 1..7, in [0,448)
  u16x8 stg[3];
  float avp = 0.f;

  auto LD = [&](int c) {    // T14: issue chunk-c loads into regs, consumed next ph1
    int t0 = c * C_;
    if (wv == 0) {
      avp = (lane < 32) ? abase[(size_t)(t0 + lane) * 16]
                        : bbase[(size_t)(t0 + lane - 32) * 16];
    } else {
      #pragma unroll
      for (int it = 0; it < 3; ++it) {
        int j = jb + it * 448;
        if (j < 512) {
          int t = j >> 4, g = j & 15;
          stg[it] = *(const u16x8*)(kbase + (size_t)(t0 + t) * QKVC + g * 8);
        } else if (j < 1024) {
          int j2 = j - 512, t = j2 >> 4, g = j2 & 15;
          stg[it] = *(const u16x8*)(qbase + (size_t)(t0 + t) * QKVC + g * 8);
        } else if (j < 1152) {
          int j2 = j - 1024, t = j2 >> 2, rg = j2 & 3;
          stg[it] = *(const u16x8*)(vbase + (size_t)(t0 + t) * QKVC + rg * 8);
        }
      }
    }
  };

  LD(0);

  for (int c = 0; c < NC_; ++c) {
    int t0 = c * C_;

    // ---- ph1: state image + staging writes + gates; prefetch c+1 ----
    #pragma unroll
    for (int rt = 0; rt < 2; ++rt)
      #pragma unroll
      for (int r = 0; r < 4; ++r) {
        float s = st[rt][r];
        u16 hi = f2b(s);
        float lo = s - b2f(hi);
        int row = rt * 16 + quad * 4 + r;
        int col = wv * 16 + l16;
        Sh[row][col] = hi;
        Sl[row][col] = f2b(lo);
      }

    if (wv == 0) {
      float av = avp;
      float p = av;
      #pragma unroll
      for (int d = 1; d < 32; d <<= 1) {
        float up = __shfl_up(p, d);
        if (lane >= d && lane < 32) p *= up;
      }
      float pm1 = __shfl_up(p, 1);
      float bt = __shfl(av, lane + 32);
      if (lane < 32) {
        if (lane == 0) pm1 = 1.f;
        f32x4 g;
        g[0] = bt * pm1; g[1] = bt; g[2] = 1.0f / p; g[3] = p;
        *(f32x4*)PL4[lane] = g;
      }
    } else {
      #pragma unroll
      for (int it = 0; it < 3; ++it) {
        int j = jb + it * 448;
        if (j < 512) {
          int t = j >> 4, g = j & 15;
          *(u16x8*)&Kim[t][g * 8] = stg[it];
          int blk = ((t >> 3) ^ (g & 3)) << 3;
          int tl = t & 7;
          #pragma unroll
          for (int e = 0; e < 8; ++e)
            KT[g * 8 + e][blk + tl] = stg[it][e];
        } else if (j < 1024) {
          int j2 = j - 512, t = j2 >> 4, g = j2 & 15;
          *(u16x8*)&Qim[t][g * 8] = stg[it];
        } else if (j < 1152) {
          int j2 = j - 1024, t = j2 >> 2, rg = j2 & 3;
          *(u16x8*)&Vim[t][rg * 8] = stg[it];
        }
      }
    }
    if (c + 1 < NC_) LD(c + 1);
    __syncthreads();

    // ---- ph2: KK / KQ / SK0 / SQ0 over 8 waves (14 disjoint tile-jobs) ----
    {
      auto dotKK = [&](int mt, int nt) {
        f32x4 acc = {0.f,0.f,0.f,0.f};
        #pragma unroll
        for (int ks = 0; ks < 4; ++ks) {
          bf16x8 A = *(const bf16x8*)&Kim[mt * 16 + l16][ks * 32 + quad * 8];
          bf16x8 B = *(const bf16x8*)&Kim[nt * 16 + l16][ks * 32 + quad * 8];
          acc = MFMA16(A, B, acc);
        }
        #pragma unroll
        for (int r = 0; r < 4; ++r) KK[mt * 16 + quad * 4 + r][nt * 16 + l16] = acc[r];
      };
      auto dotKQ = [&](int mt, int nt) {
        f32x4 acc = {0.f,0.f,0.f,0.f};
        #pragma unroll
        for (int ks = 0; ks < 4; ++ks) {
          bf16x8 A = *(const bf16x8*)&Qim[mt * 16 + l16][ks * 32 + quad * 8];
          bf16x8 B = *(const bf16x8*)&Kim[nt * 16 + l16][ks * 32 + quad * 8];
          acc = MFMA16(A, B, acc);
        }
        #pragma unroll
        for (int r = 0; r < 4; ++r) KQ[mt * 16 + quad * 4 + r][nt * 16 + l16] = acc[r];
      };
      auto dotS = [&](const u16 (*Aarr)[136], int tt, int rr, float (*OUT)[33]) {
        f32x4 acc = {0.f,0.f,0.f,0.f};
        #pragma unroll
        for (int ks = 0; ks < 4; ++ks) {
          bf16x8 A  = *(const bf16x8*)&Aarr[tt * 16 + l16][ks * 32 + quad * 8];
          bf16x8 Bh = *(const bf16x8*)&Sh[rr * 16 + l16][ks * 32 + quad * 8];
          bf16x8 Bl = *(const bf16x8*)&Sl[rr * 16 + l16][ks * 32 + quad * 8];
          acc = MFMA16(A, Bh, acc);
          acc = MFMA16(A, Bl, acc);
        }
        #pragma unroll
        for (int r = 0; r < 4; ++r) OUT[tt * 16 + quad * 4 + r][rr * 16 + l16] = acc[r];
      };
      switch (wv) {
        case 0: dotS(Kim, 0, 0, SK0); dotKK(0, 0); break;
        case 1: dotS(Kim, 0, 1, SK0); dotKK(1, 0); break;
        case 2: dotS(Kim, 1, 0, SK0); dotKK(1, 1); break;
        case 3: dotS(Kim, 1, 1, SK0); dotKQ(0, 0); break;
        case 4: dotS(Qim, 0, 0, SQ0); dotKQ(1, 0); break;
        case 5: dotS(Qim, 0, 1, SQ0); dotKQ(1, 1); break;
        case 6: dotS(Qim, 1, 0, SQ0); break;
        default: dotS(Qim, 1, 1, SQ0); break;
      }
    }
    __syncthreads();

    // ---- ph3a: wave0 shared solve (vectorized KK reads) || waves4-7 G frags ----
    union { u16x8 u; bf16x8 b; } gh, gl;
    int omt = (wv - 4) >> 1, ont = (wv - 4) & 1;     // output tile for wv>=4
    if (wv == 0) {
      if (lane < 32) {
        float ub[C_];
        #pragma unroll
        for (int t = 0; t < C_; ++t) {
          f32x4 g = *(const f32x4*)PL4[t];
          float u = g[0] * SK0[t][lane] - g[1] * b2f(Vim[t][lane]);
          float acc = 0.f;
          #pragma unroll
          for (int i4 = 0; i4 < t / 4; ++i4) {
            f32x4 kk = *(const f32x4*)&KK[t][i4 * 4];   // uniform b128 broadcast
            acc = fmaf(kk[0], ub[i4 * 4 + 0], acc);
            acc = fmaf(kk[1], ub[i4 * 4 + 1], acc);
            acc = fmaf(kk[2], ub[i4 * 4 + 2], acc);
            acc = fmaf(kk[3], ub[i4 * 4 + 3], acc);
          }
          #pragma unroll
          for (int i = (t / 4) * 4; i < t; ++i)
            acc = fmaf(KK[t][i], ub[i], acc);
          u = fmaf(-g[0], acc, u);
          U[t][lane] = u;
          ub[t] = g[2] * u;
        }
      }
    } else if (wv >= 4) {
      int trow = omt * 16 + l16;
      float Pt = PL4[trow][3];
      #pragma unroll
      for (int e = 0; e < 8; ++e) {
        int i = quad * 8 + e;
        float gv = (i <= trow) ? (-Pt * PL4[i][2] * KQ[trow][i]) : 0.f;
        u16 h2 = f2b(gv);
        gh.u[e] = h2; gl.u[e] = f2b(gv - b2f(h2));
      }
    }
    __syncthreads();

    // ---- ph3b: all waves state update from shared U; waves 4-7 outputs ----
    {
      float PL31 = PL4[31][3];

      #pragma unroll
      for (int rt = 0; rt < 2; ++rt) {
        union { u16x8 u; bf16x8 b; } ah, al;
        #pragma unroll
        for (int e = 0; e < 8; ++e) {
          int i = quad * 8 + e;
          float uv = U[i][rt * 16 + l16];
          float ucv = -PL31 * PL4[i][2] * uv;
          u16 hh = f2b(ucv);
          ah.u[e] = hh; al.u[e] = f2b(ucv - b2f(hh));
        }
        int col = wv * 16 + l16;
        bf16x8 Bk = *(const bf16x8*)&KT[col][(quad ^ ((col >> 3) & 3)) << 3];
        f32x4 cacc;
        #pragma unroll
        for (int r = 0; r < 4; ++r) cacc[r] = PL31 * st[rt][r];
        cacc = MFMA16(ah.b, Bk, cacc);
        cacc = MFMA16(al.b, Bk, cacc);
        st[rt] = cacc;
      }

      if (wv >= 4) {
        union { u16x8 u; bf16x8 b; } uth, utl;
        #pragma unroll
        for (int e = 0; e < 8; ++e) {
          int i = quad * 8 + e;
          float uv = U[i][ont * 16 + l16];
          u16 h1 = f2b(uv);
          uth.u[e] = h1; utl.u[e] = f2b(uv - b2f(h1));
        }
        f32x4 oacc;
        #pragma unroll
        for (int r = 0; r < 4; ++r) {
          int t = omt * 16 + quad * 4 + r;
          oacc[r] = PL4[t][3] * SQ0[t][ont * 16 + l16];
        }
        oacc = MFMA16(gh.b, uth.b, oacc);
        oacc = MFMA16(gh.b, utl.b, oacc);
        oacc = MFMA16(gl.b, uth.b, oacc);
        #pragma unroll
        for (int r = 0; r < 4; ++r) {
          int t = omt * 16 + quad * 4 + r;
          obase[(size_t)(t0 + t) * 2048 + ont * 16 + l16] = f2b(oacc[r]);
        }
      }
    }
    __syncthreads();
  }
}

// ---------------- LayerNorm(DV) * sigmoid(g) ----------------
__global__ __launch_bounds__(256) void ln_gate_k(const u16* __restrict__ o_raw,
                                                 const u16* __restrict__ g,
                                                 const u16* __restrict__ lnw,
                                                 const u16* __restrict__ lnb,
                                                 u16* __restrict__ o_ln)
{
  int gid = blockIdx.x * 4 + (threadIdx.x >> 6);
  int lane = threadIdx.x & 63;
  int row = gid >> 4, h = gid & 15;
  size_t ofs = (size_t)row * 2048 + h * 128 + lane * 2;
  unsigned int e2 = *(const unsigned int*)(o_raw + ofs);
  float ex = b2f((u16)(e2 & 0xffff)), ey = b2f((u16)(e2 >> 16));
  float s = ex + ey, ss = ex * ex + ey * ey;
  #pragma unroll
  for (int m = 1; m < 64; m <<= 1) { s += __shfl_xor(s, m); ss += __shfl_xor(ss, m); }
  float mean = s * (1.f / 128.f);
  float var  = ss * (1.f / 128.f) - mean * mean;
  float rstd = rsqrtf(fmaxf(var, 0.f) + 1e-5f);
  float w0 = b2f(lnw[lane * 2]), w1 = b2f(lnw[lane * 2 + 1]);
  float b0 = b2f(lnb[lane * 2]), b1 = b2f(lnb[lane * 2 + 1]);
  unsigned int g2 = *(const unsigned int*)(g + ofs);
  float g0 = sigm(b2f((u16)(g2 & 0xffff))), g1 = sigm(b2f((u16)(g2 >> 16)));
  float r0 = ((ex - mean) * rstd * w0 + b0) * g0;
  float r1 = ((ey - mean) * rstd * w1 + b1) * g1;
  *(unsigned int*)(o_ln + ofs) = (unsigned int)f2b(r0) | ((unsigned int)f2b(r1) << 16);
}

// ---------------- host launch ----------------
extern "C" void kernel_launch(void* const* d_in, const int* in_sizes, int n_in,
                              void* d_out, int out_size, void* d_ws, size_t ws_size,
                              hipStream_t stream)
{
  const float* x   = (const float*)d_in[0];
  const float* Wq  = (const float*)d_in[1];
  const float* Wk  = (const float*)d_in[2];
  const float* Wv  = (const float*)d_in[3];
  const float* Wa  = (const float*)d_in[4];
  const float* ba  = (const float*)d_in[5];
  const float* Wb  = (const float*)d_in[6];
  const float* bb  = (const float*)d_in[7];
  const float* Wg  = (const float*)d_in[8];
  const float* Wo  = (const float*)d_in[9];
  const float* qcw = (const float*)d_in[10];
  const float* qcb = (const float*)d_in[11];
  const float* kcw = (const float*)d_in[12];
  const float* kcb = (const float*)d_in[13];
  const float* vcw = (const float*)d_in[14];
  const float* vcb = (const float*)d_in[15];
  const float* lnw = (const float*)d_in[16];
  const float* lnb = (const float*)d_in[17];
  (void)in_sizes; (void)n_in; (void)out_size;

  char* ws = (char*)d_ws;
  size_t off = 0;
  auto alloc = [&](size_t bytes) -> void* {
    void* p = ws + off; off += (bytes + 255) & ~(size_t)255; return p;
  };
  u16* WT    = (u16*)alloc((size_t)3 * HID_ * HID_ * 2);
  u16* WabT  = (u16*)alloc((size_t)32 * HID_ * 2);
  u16* xc    = (u16*)alloc((size_t)BT_ * HID_ * 2);
  u16* canon = (u16*)alloc((size_t)31008 * 2);
  u16* post  = (u16*)alloc((size_t)BT_ * QKVC * 2);
  float* abuf = (float*)alloc((size_t)2 * BT_ * 16 * 4);
  size_t base_off = off;

  size_t fused_need = base_off + (((size_t)BT_ * QKVC * 2 + 255) & ~(size_t)255);
  int fused = (fused_need <= ws_size);
  u16* preC;
  if (fused) preC = (u16*)alloc((size_t)BT_ * QKVC * 2);
  else       preC = (u16*)alloc((size_t)BT_ * HID_ * 2 * 2);
  if (off > ws_size) return;

  u16* cw_c  = canon;
  u16* cb_c  = canon + 24576;
  u16* ba_c  = canon + 30720;
  u16* bb_c  = canon + 30736;
  u16* lnw_c = canon + 30752;
  u16* lnb_c = canon + 30880;

  u16* o_raw = preC;
  u16* g_raw = post;
  u16* o_ln  = post + (size_t)BT_ * HID_;
  u16* WTg   = WT;

  dim3 tb(256), tb5(512);

  cvt_x_k<<<dim3(4096), tb, 0, stream>>>((const f32x4*)x, (u16x4*)xc, BT_ * HID_ / 4);
  cvt_small_k<<<dim3(122), tb, 0, stream>>>(qcw, kcw, vcw, qcb, kcb, vcb, ba, bb, lnw, lnb, canon);

  transpose_b<<<dim3(64, 64, 3), tb, 0, stream>>>(Wq, Wk, Wv, WT, HID_, HID_);
  transpose_b<<<dim3(1, 64, 2), tb, 0, stream>>>(Wa, Wb, Wb, WabT, HID_, 16);

  if (fused) {
    gemm256<<<dim3(QKVC / GBN, BT_ / GBM), tb5, 0, stream>>>(xc, HID_, WT, HID_, preC, QKVC, HID_, 0);
    for (int b = 0; b < B_; ++b)
      conv_silu_k<<<dim3(T_ * (QKVC / 8) / 256), tb, 0, stream>>>(
          preC + (size_t)b * T_ * QKVC, cw_c, cb_c, post + (size_t)b * T_ * QKVC);
  } else {
    for (int b = 0; b < B_; ++b) {
      const u16* xb = xc + (size_t)b * T_ * HID_;
      gemm256<<<dim3(QKVC / GBN, T_ / GBM), tb5, 0, stream>>>(xb, HID_, WT, HID_, preC, QKVC, HID_, 0);
      conv_silu_k<<<dim3(T_ * (QKVC / 8) / 256), tb, 0, stream>>>(
          preC, cw_c, cb_c, post + (size_t)b * T_ * QKVC);
    }
  }

  transpose_b<<<dim3(64, 64, 2), tb, 0, stream>>>(Wg, Wo, Wo, WTg, HID_, HID_);

  ab_k<<<dim3(BT_ / 8), tb, 0, stream>>>(xc, WabT, ba_c, bb_c, abuf);

  // chunked scan: 256 blocks x 512 threads (8 waves/block; multi-block/CU does not
  // co-schedule -- R5 -- so occupancy comes from block size)
  chunk_scan_k<<<dim3(256), tb5, 0, stream>>>(post, abuf, o_raw);

  gemm256<<<dim3(HID_ / GBN, BT_ / GBM), tb5, 0, stream>>>(xc, HID_, WTg, HID_, g_raw, HID_, HID_, 0);

  ln_gate_k<<<dim3(BT_ * H_ / 4), tb, 0, stream>>>(o_raw, g_raw, lnw_c, lnb_c, o_ln);

  gemm256<<<dim3(HID_ / GBN, BT_ / GBM), tb5, 0, stream>>>(o_ln, HID_,
      WT + (size_t)HID_ * HID_, HID_, d_out, HID_, HID_, 1);
}